// Round 11
// baseline (152.622 us; speedup 1.0000x reference)
//
#include <hip/hip_runtime.h>
#include <hip/hip_bf16.h>

__device__ __forceinline__ float sigm(float x) { return 1.f / (1.f + expf(-x)); }
__device__ __forceinline__ float lrelu(float x) { return x > 0.f ? x : 0.2f * x; }
__device__ __forceinline__ float eluf(float x) { return x > 0.f ? x : expf(x) - 1.f; }

#define NEGF (-9e15f)
#define MAXD 64   // max supported out-degree; P(deg>64) ~ 1e-40 for Binom(4096,1/512)

__device__ __forceinline__ float wave_sum(float v) {
    #pragma unroll
    for (int off = 32; off >= 1; off >>= 1) v += __shfl_xor(v, off);
    return v;
}
__device__ __forceinline__ float wave_max(float v) {
    #pragma unroll
    for (int off = 32; off >= 1; off >>= 1) v = fmaxf(v, __shfl_xor(v, off));
    return v;
}

// ---------------- K_setup: block-role fused independent preprocessing ----------------
// grid 176, block 256:
//   b 0..15   : vecs (vs1/vd1/ve1 for head b)
//   b 16..31  : ve2 (128 outputs/block)
//   b 32..47  : winner := -1 (clear; scatter happens next dispatch)
//   b 48..175 : SingleNodeAttention h + gate1 (4 nodes/block)
__global__ void k_setup(const float* __restrict__ Wg, const float* __restrict__ Weg,
                        const float* __restrict__ asrc, const float* __restrict__ adst,
                        const float* __restrict__ aedge, const float* __restrict__ Weo,
                        const float* __restrict__ aoe,
                        const float* __restrict__ feat, const float* __restrict__ Wsn,
                        const float* __restrict__ asn, const float* __restrict__ g1W,
                        const float* __restrict__ g1b,
                        float* __restrict__ vs1, float* __restrict__ vd1, float* __restrict__ ve1,
                        float* __restrict__ ve2, int* __restrict__ winner,
                        float* __restrict__ h, float* __restrict__ gate1) {
    int b = blockIdx.x, t = threadIdx.x, w = t >> 6, l = t & 63;
    __shared__ float fr[4][64];
    if (b < 16) {
        int hd = b;
        float s0 = asrc[hd * 128 + l],  s1 = asrc[hd * 128 + 64 + l];
        float d0 = adst[hd * 128 + l],  d1 = adst[hd * 128 + 64 + l];
        float e0 = aedge[hd * 128 + l], e1 = aedge[hd * 128 + 64 + l];
        for (int i = w; i < 64; i += 4) {
            const float* Wr = Wg  + ((size_t)hd * 64 + i) * 128;
            const float* Er = Weg + ((size_t)hd * 64 + i) * 128;
            float w1 = Wr[l], w2 = Wr[64 + l];
            float q1 = Er[l], q2 = Er[64 + l];
            float pS = wave_sum(w1 * s0 + w2 * s1);
            float pD = wave_sum(w1 * d0 + w2 * d1);
            float pE = wave_sum(q1 * e0 + q2 * e1);
            if (l == 0) { vs1[hd * 64 + i] = pS; vd1[hd * 64 + i] = pD; ve1[hd * 64 + i] = pE; }
        }
    } else if (b < 32) {
        int base = (b - 16) * 128;
        float a0 = aoe[l], a1 = aoe[64 + l];
        for (int k = 0; k < 32; k++) {
            int c = base + w * 32 + k;
            const float* Wr = Weo + (size_t)c * 128;
            float p = wave_sum(Wr[l] * a0 + Wr[64 + l] * a1);
            if (l == 0) ve2[c] = p;
        }
    } else if (b < 48) {
        int base = (b - 32) * 4096;
        #pragma unroll
        for (int k = 0; k < 16; k++) winner[base + k * 256 + t] = -1;
    } else {
        int n = (b - 48) * 4 + w;
        fr[w][l] = feat[n * 64 + l];
        __syncthreads();
        float acc = 0.f;
        #pragma unroll 8
        for (int i = 0; i < 64; i++) acc += fr[w][i] * Wsn[i * 64 + l];
        float p = wave_sum(acc * asn[l]);
        float coef = sigm(lrelu(p));
        float hv = eluf(coef * acc);
        h[n * 64 + l] = hv;
        float g = wave_sum(hv * g1W[l]);
        if (l == 0) gate1[n] = sigm(g + g1b[0]);
    }
}

// ---------------- K_mid: wsum1p (b 0..7) | es1/ed1 precompute (b 8..23) | scatter (b 24..31) ----------------
// grid 32, block 512
__global__ void k_mid(const float* __restrict__ h, const float* __restrict__ gate,
                      const float* __restrict__ vs1, const float* __restrict__ vd1,
                      const int* __restrict__ ei,
                      float* __restrict__ part1, float* __restrict__ es1, float* __restrict__ ed1,
                      int* __restrict__ winner) {
    int b = blockIdx.x, t = threadIdx.x;
    if (b < 8) {
        int nb = b, w = t >> 6, l = t & 63;
        __shared__ float mx[8], sm[8], al[512], pt[8][64];
        float g = gate[t];
        float m = wave_max(g);
        if (l == 0) mx[w] = m;
        __syncthreads();
        m = mx[0];
        #pragma unroll
        for (int i = 1; i < 8; i++) m = fmaxf(m, mx[i]);
        float p = expf(g - m);
        float Z = wave_sum(p);
        if (l == 0) sm[w] = Z;
        __syncthreads();
        Z = 0.f;
        #pragma unroll
        for (int i = 0; i < 8; i++) Z += sm[i];
        al[t] = p / Z;
        __syncthreads();
        int r0 = nb * 64 + w * 8;
        float acc = 0.f;
        #pragma unroll
        for (int r = 0; r < 8; r++) acc += al[r0 + r] * h[(r0 + r) * 64 + l];
        pt[w][l] = acc;
        __syncthreads();
        if (t < 64) {
            float o = 0.f;
            #pragma unroll
            for (int q = 0; q < 8; q++) o += pt[q][t];
            part1[nb * 64 + t] = o;
        }
    } else if (b < 24) {
        __shared__ float vsT[64][17], vdT[64][17];
        for (int idx = t; idx < 1024; idx += 512) {
            int i = idx & 63, hd = idx >> 6;
            vsT[i][hd] = vs1[hd * 64 + i];
            vdT[i][hd] = vd1[hd * 64 + i];
        }
        __syncthreads();
        int idx = (b - 8) * 512 + t;     // 0..8191
        int n = idx >> 4, hd = idx & 15;
        const float* hr = h + n * 64;
        float aS = 0.f, aD = 0.f;
        #pragma unroll 8
        for (int i = 0; i < 64; i++) {
            float hv = hr[i];
            aS += hv * vsT[i][hd];
            aD += hv * vdT[i][hd];
        }
        es1[hd * 512 + n] = aS;
        ed1[hd * 512 + n] = aD;
    } else {
        int e = (b - 24) * 512 + t;      // 0..4095
        int s = ei[e] >> 1, d = ei[4096 + e] >> 1;
        atomicMax(&winner[s * 256 + d], e);   // last edge index wins (np .set semantics)
    }
}

// ---------------- K_attn_z: sparse GAT1 attention -> z[s][hd][0:64] = sum_j a*h[d_j] ----------------
// grid 512 (s), block 512
__global__ void k_attn_z(const float* __restrict__ adj, const float* __restrict__ n2n,
                         const float* __restrict__ h, const float* __restrict__ ve1,
                         const float* __restrict__ es1, const float* __restrict__ ed1,
                         float* __restrict__ z) {
    int s = blockIdx.x, t = threadIdx.x, w = t >> 6, l = t & 63;
    __shared__ float vlT[64][17];
    __shared__ float hrow[MAXD][65], nrow[MAXD][65];
    __shared__ float eh[16][65], ah[16][65];
    __shared__ float esr[16];
    __shared__ int dlist[MAXD];
    __shared__ int wbase[8];
    __shared__ int nnz_s;

    for (int idx = t; idx < 1024; idx += 512) vlT[idx & 63][idx >> 6] = ve1[(idx >> 6) * 64 + (idx & 63)];
    if (t < 16) esr[t] = es1[t * 512 + s];
    float a = adj[s * 512 + t];
    unsigned long long mask = __ballot(a > 0.f);
    if (l == 0) wbase[w] = __popcll(mask);
    __syncthreads();
    if (t == 0) {
        int run = 0;
        #pragma unroll
        for (int i = 0; i < 8; i++) { int c = wbase[i]; wbase[i] = run; run += c; }
        nnz_s = run;
    }
    __syncthreads();
    if (a > 0.f) {
        int slot = wbase[w] + __popcll(mask & ((1ULL << l) - 1ULL));
        if (slot < MAXD) dlist[slot] = t;
    }
    __syncthreads();
    int nnz = min(nnz_s, MAXD);

    if (nnz == 0) {
        __shared__ float part[8][64];
        int i = t & 63, q = t >> 6;
        float acc = 0.f;
        for (int d = q * 64; d < q * 64 + 64; d++) acc += h[d * 64 + i];
        part[q][i] = acc;
        __syncthreads();
        if (t < 64) {
            float sum = 0.f;
            #pragma unroll
            for (int q2 = 0; q2 < 8; q2++) sum += part[q2][t];
            float v = sum * (1.f / 512.f);
            for (int hd = 0; hd < 16; hd++) z[(size_t)s * 1024 + hd * 64 + t] = v;
        }
        return;
    }

    for (int base = 0; base < nnz; base += 8) {
        int j = base + (t >> 6);
        if (j < nnz) {
            int d = dlist[j];
            hrow[j][l] = h[d * 64 + l];
            nrow[j][l] = n2n[((size_t)s * 512 + d) * 64 + l];
        }
    }
    __syncthreads();
    for (int jb = 0; jb < nnz; jb += 32) {
        int j = jb + (t >> 4), hd = t & 15;
        if (j < nnz) {
            float ee = 0.f;
            #pragma unroll 8
            for (int i = 0; i < 64; i++) ee += nrow[j][i] * vlT[i][hd];
            eh[hd][j] = lrelu(esr[hd] + ed1[hd * 512 + dlist[j]] + ee);
        }
    }
    __syncthreads();
    if (t < 16) {
        float m = -1e30f;
        for (int j = 0; j < nnz; j++) m = fmaxf(m, eh[t][j]);
        float Z = 0.f;
        for (int j = 0; j < nnz; j++) { float p = expf(eh[t][j] - m); ah[t][j] = p; Z += p; }
        float inv = 1.f / Z;
        for (int j = 0; j < nnz; j++) ah[t][j] *= inv;
    }
    __syncthreads();
    int hd = t >> 5, i0 = t & 31;
    float a0 = 0.f, a1 = 0.f;
    for (int j = 0; j < nnz; j++) {
        float aj = ah[hd][j];
        a0 += aj * hrow[j][i0];
        a1 += aj * hrow[j][i0 + 32];
    }
    z[(size_t)s * 1024 + hd * 64 + i0]      = a0;
    z[(size_t)s * 1024 + hd * 64 + i0 + 32] = a1;
}

// ---------------- K_houtp: hout1 = elu(z@Wg) (LDS only) + edge_pool1 + gate2 ----------------
// grid 128 (4 rows each), block 512: rq = t>>7 owns row rq; pool pairs g = t>>8
__global__ void k_houtp(const float* __restrict__ z, const float* __restrict__ Wg,
                        const float* __restrict__ Wp1, const float* __restrict__ bp1,
                        const float* __restrict__ g2W, const float* __restrict__ g2b,
                        float* __restrict__ x1p, float* __restrict__ gate2) {
    int b = blockIdx.x, t = threadIdx.x;
    __shared__ float zt[4][1024];    // 16KB
    __shared__ float xr[4][2048];    // 32KB
    __shared__ float sgp[8], red[8];
    int s0 = b * 4;
    for (int idx = t; idx < 4096; idx += 512)
        zt[idx >> 10][idx & 1023] = z[(size_t)(s0 + (idx >> 10)) * 1024 + (idx & 1023)];
    __syncthreads();
    int rq = t >> 7, c = t & 127;
    for (int hd = 0; hd < 16; hd++) {
        const float* W = Wg + (size_t)hd * 8192 + c;
        const float* zr = &zt[rq][hd * 64];
        float acc = 0.f;
        #pragma unroll 8
        for (int i = 0; i < 64; i++) acc += zr[i] * W[(size_t)i * 128];
        xr[rq][hd * 128 + c] = eluf(acc);
    }
    __syncthreads();
    // pool: pair g = t>>8 (rows 2g, 2g+1 -> x1p row 2b+g), 256 threads/pair
    int g = t >> 8, tt = t & 255;
    float p = 0.f;
    #pragma unroll
    for (int m = 0; m < 8; m++) {
        int f = tt + 256 * m;
        p += xr[2 * g][f] * Wp1[f] + xr[2 * g + 1][f] * Wp1[2048 + f];
    }
    p = wave_sum(p);
    if ((t & 63) == 0) sgp[t >> 6] = p;
    __syncthreads();
    float sc = sigm(sgp[4 * g] + sgp[4 * g + 1] + sgp[4 * g + 2] + sgp[4 * g + 3] + bp1[0]);
    int k = 2 * b + g;
    float pg = 0.f;
    #pragma unroll
    for (int m = 0; m < 8; m++) {
        int f = tt + 256 * m;
        float v = xr[2 * g][f] + xr[2 * g + 1][f];
        x1p[(size_t)k * 2048 + f] = v * sc;
        pg += v * g2W[f];
    }
    pg = wave_sum(pg);
    if ((t & 63) == 0) red[t >> 6] = pg;
    __syncthreads();
    if (tt == 0) gate2[k] = sigm(sc * (red[4 * g] + red[4 * g + 1] + red[4 * g + 2] + red[4 * g + 3]) + g2b[0]);
}

// ---------------- K_big2e: wh2 (b 0..127) | wsum2p (b 128..143) | edot (b 144..399) ----------------
// grid 400, block 1024
__global__ void k_big2e(const float* __restrict__ x, const float* __restrict__ Wo,
                        const float* __restrict__ aos, const float* __restrict__ aod,
                        const float* __restrict__ gate2, const float* __restrict__ eattr,
                        const float* __restrict__ Weg, const float* __restrict__ ve2,
                        float* __restrict__ Wh2, float* __restrict__ es2, float* __restrict__ ed2,
                        float* __restrict__ part2, float* __restrict__ d2) {
    int b = blockIdx.x, t = threadIdx.x;
    if (b < 128) {
        int n0 = b * 2;
        int ks = t >> 7, c = t & 127;
        __shared__ float xr[2][2048];
        __shared__ float part[8][2][128];
        __shared__ float rs[4], rd[4];
        for (int idx = t; idx < 4096; idx += 1024) xr[idx >> 11][idx & 2047] = x[(size_t)n0 * 2048 + idx];
        __syncthreads();
        float a0 = 0.f, a1 = 0.f;
        const float* W  = Wo + (size_t)(ks * 256) * 128 + c;
        const float* x0 = xr[0] + ks * 256;
        const float* x1 = xr[1] + ks * 256;
        #pragma unroll 8
        for (int i = 0; i < 256; i++) { float w = W[(size_t)i * 128]; a0 += x0[i] * w; a1 += x1[i] * w; }
        part[ks][0][c] = a0;
        part[ks][1][c] = a1;
        __syncthreads();
        if (t < 256) {
            int r = t >> 7, cc = t & 127;
            float a = 0.f;
            #pragma unroll
            for (int k = 0; k < 8; k++) a += part[k][r][cc];
            Wh2[(n0 + r) * 128 + cc] = a;
            float ps = wave_sum(a * aos[cc]);
            float pd = wave_sum(a * aod[cc]);
            if ((t & 63) == 0) { rs[t >> 6] = ps; rd[t >> 6] = pd; }
        }
        __syncthreads();
        if (t == 0) { es2[n0] = rs[0] + rs[1]; ed2[n0] = rd[0] + rd[1]; }
        if (t == 1) { es2[n0 + 1] = rs[2] + rs[3]; ed2[n0 + 1] = rd[2] + rd[3]; }
    } else if (b < 144) {
        int wb = b - 128;                 // 0..15
        int grp = t >> 8, tt = t & 255;   // 4 groups of 256
        int tile = wb * 4 + grp;          // 0..63
        int cb = tile >> 3, nb = tile & 7;
        __shared__ float mx[4][4], sm[4][4], al[4][256];
        int w4 = tt >> 6, l = tt & 63;
        float g = gate2[tt];
        float m = wave_max(g);
        if (l == 0) mx[grp][w4] = m;
        __syncthreads();
        m = fmaxf(fmaxf(mx[grp][0], mx[grp][1]), fmaxf(mx[grp][2], mx[grp][3]));
        float p = expf(g - m);
        float Z = wave_sum(p);
        if (l == 0) sm[grp][w4] = Z;
        __syncthreads();
        Z = sm[grp][0] + sm[grp][1] + sm[grp][2] + sm[grp][3];
        al[grp][tt] = p / Z;
        __syncthreads();
        int c = cb * 256 + tt;
        int n0 = nb * 32;
        float acc = 0.f;
        #pragma unroll 8
        for (int n = n0; n < n0 + 32; n++) acc += al[grp][n] * x[(size_t)n * 2048 + c];
        part2[nb * 2048 + c] = acc;
    } else {
        // edot: 16 edges/block; thread = (head hd = t>>6 in 0..15, q = t&63 -> float2 channels)
        // wave w == head hd (64 lanes x 2 ch = 128 ch/head); float2 acc[16] = 32 VGPRs (R9-proven budget)
        int e0 = (b - 144) * 16;
        int hd = t >> 6, l = t & 63;
        __shared__ float ea[16][64];
        __shared__ float sd[16][16];
        ea[t >> 6][t & 63] = eattr[(size_t)(e0 + (t >> 6)) * 64 + (t & 63)];
        __syncthreads();
        float2 acc[16];
        #pragma unroll
        for (int r = 0; r < 16; r++) acc[r] = make_float2(0.f, 0.f);
        const float2* W2 = (const float2*)(Weg + (size_t)hd * 8192) + l;   // row stride = 64 float2
        #pragma unroll 4
        for (int i = 0; i < 64; i++) {
            float2 wv = W2[i * 64];
            #pragma unroll
            for (int r = 0; r < 16; r++) {
                float a = ea[r][i];
                acc[r].x += a * wv.x;
                acc[r].y += a * wv.y;
            }
        }
        float2 v2 = ((const float2*)ve2)[hd * 64 + l];
        #pragma unroll
        for (int r = 0; r < 16; r++) {
            float p = eluf(acc[r].x) * v2.x + eluf(acc[r].y) * v2.y;
            p = wave_sum(p);
            if (l == 0) sd[r][hd] = p;
        }
        __syncthreads();
        if (t < 16) {
            float s16 = 0.f;
            #pragma unroll
            for (int k = 0; k < 16; k++) s16 += sd[t][k];
            d2[e0 + t] = s16;
        }
    }
}

// ---------------- K_fin: attn2 (b 0..255) | wsumr (b 256..264) ----------------
// grid 265, block 256
__global__ void k_fin(const int* __restrict__ winner, const float* __restrict__ d2,
                      const float* __restrict__ es2, const float* __restrict__ ed2,
                      const float* __restrict__ Wh2, const float* __restrict__ part1,
                      const float* __restrict__ part2,
                      float* __restrict__ hout2, float* __restrict__ out) {
    int b = blockIdx.x, t = threadIdx.x;
    if (b < 256) {
        int s = b, w = t >> 6, l = t & 63;
        __shared__ float mx[4], sm[4], at[256], part[2][128];
        int win = winner[s * 256 + t];
        float e;
        if (win >= 0) e = lrelu(es2[s] + ed2[t] + d2[win]);
        else e = NEGF;
        float m = wave_max(e);
        if (l == 0) mx[w] = m;
        __syncthreads();
        m = fmaxf(fmaxf(mx[0], mx[1]), fmaxf(mx[2], mx[3]));
        float p = expf(e - m);
        float Z = wave_sum(p);
        if (l == 0) sm[w] = Z;
        __syncthreads();
        Z = sm[0] + sm[1] + sm[2] + sm[3];
        at[t] = p / Z;
        __syncthreads();
        int c = t & 127, hf = t >> 7;
        float acc = 0.f;
        for (int d = hf * 128; d < hf * 128 + 128; d++)
            acc += at[d] * Wh2[d * 128 + c];
        part[hf][c] = acc;
        __syncthreads();
        if (t < 128) hout2[s * 128 + t] = part[0][t] + part[1][t];   // concat=False: no elu
    } else if (b == 256) {
        if (t < 64) {
            float o = 0.f;
            #pragma unroll
            for (int nb = 0; nb < 8; nb++) o += part1[nb * 64 + t];
            out[t] = o;
        }
    } else {
        int c = (b - 257) * 256 + t;
        float o = 0.f;
        #pragma unroll
        for (int nb = 0; nb < 8; nb++) o += part2[nb * 2048 + c];
        out[64 + c] = o;
    }
}

// ---------------- K_tail: edge_pool2 + gate3 + global-attn3, single block ----------------
// grid 1, block 512
__global__ void k_tail(const float* __restrict__ hout2, const float* __restrict__ Wp,
                       const float* __restrict__ bp, const float* __restrict__ g3W,
                       const float* __restrict__ g3b, float* __restrict__ out) {
    int t = threadIdx.x, w = t >> 6, l = t & 63;
    __shared__ float x2s[128][129];
    __shared__ float gt[128];
    __shared__ float mx[2], sm[2], al[128], part[4][128];
    float bpv = bp[0], g3bv = g3b[0];
    for (int rr = 0; rr < 16; rr++) {
        int k = w * 16 + rr;
        float a0  = hout2[(size_t)(2 * k) * 128 + l];
        float a0b = hout2[(size_t)(2 * k) * 128 + 64 + l];
        float a1  = hout2[(size_t)(2 * k + 1) * 128 + l];
        float a1b = hout2[(size_t)(2 * k + 1) * 128 + 64 + l];
        float p = a0 * Wp[l] + a0b * Wp[64 + l] + a1 * Wp[128 + l] + a1b * Wp[192 + l];
        p = wave_sum(p);
        float sc = sigm(p + bpv);
        float v  = (a0 + a1) * sc;
        float vb = (a0b + a1b) * sc;
        x2s[k][l] = v;
        x2s[k][64 + l] = vb;
        float g = wave_sum(v * g3W[l] + vb * g3W[64 + l]);
        if (l == 0) gt[k] = sigm(g + g3bv);
    }
    __syncthreads();
    if (t < 128) {
        float g = gt[t];
        float m = wave_max(g);
        if (l == 0) mx[w] = m;
    }
    __syncthreads();
    if (t < 128) {
        float g = gt[t];
        float m = fmaxf(mx[0], mx[1]);
        float p = expf(g - m);
        float Z = wave_sum(p);
        if (l == 0) sm[w] = Z;
        al[t] = p;
    }
    __syncthreads();
    float invZ = 1.f / (sm[0] + sm[1]);
    int q = t >> 7, c = t & 127;
    float acc = 0.f;
    for (int n = q * 32; n < q * 32 + 32; n++) acc += al[n] * x2s[n][c];
    part[q][c] = acc * invZ;
    __syncthreads();
    if (t < 128) out[2112 + t] = part[0][t] + part[1][t] + part[2][t] + part[3][t];
}

extern "C" void kernel_launch(void* const* d_in, const int* in_sizes, int n_in,
                              void* d_out, int out_size, void* d_ws, size_t ws_size,
                              hipStream_t stream) {
    const float* feat  = (const float*)d_in[0];
    const int*   eidx  = (const int*)d_in[1];
    const float* eattr = (const float*)d_in[2];
    const float* adj   = (const float*)d_in[3];
    const float* n2n   = (const float*)d_in[4];
    const float* Wsn   = (const float*)d_in[5];
    const float* asn   = (const float*)d_in[6];
    const float* Wg    = (const float*)d_in[7];
    const float* Weg   = (const float*)d_in[8];
    const float* asrc  = (const float*)d_in[9];
    const float* adst  = (const float*)d_in[10];
    const float* aedge = (const float*)d_in[11];
    const float* Wp1   = (const float*)d_in[12];
    const float* bp1   = (const float*)d_in[13];
    const float* Wo    = (const float*)d_in[14];
    const float* Weo   = (const float*)d_in[15];
    const float* aos   = (const float*)d_in[16];
    const float* aod   = (const float*)d_in[17];
    const float* aoe   = (const float*)d_in[18];
    const float* Wp2   = (const float*)d_in[19];
    const float* bp2   = (const float*)d_in[20];
    const float* g1W   = (const float*)d_in[21];
    const float* g1b   = (const float*)d_in[22];
    const float* g2W   = (const float*)d_in[23];
    const float* g2b   = (const float*)d_in[24];
    const float* g3W   = (const float*)d_in[25];
    const float* g3b   = (const float*)d_in[26];
    float* out = (float*)d_out;

    char* ws = (char*)d_ws;
    float* h      = (float*)(ws + 0x0000000);   // 128KB
    float* z      = (float*)(ws + 0x0020000);   // 2MB
    float* ve1    = (float*)(ws + 0x0430000);   // 4KB
    float* ve2    = (float*)(ws + 0x0431000);   // 8KB
    float* gate1  = (float*)(ws + 0x0433000);   // 2KB
    float* gate2  = (float*)(ws + 0x0434000);   // 1KB
    float* vs1    = (float*)(ws + 0x0436000);   // 4KB
    float* vd1    = (float*)(ws + 0x0438000);   // 4KB
    float* es1    = (float*)(ws + 0x0440000);   // 32KB
    float* ed1    = (float*)(ws + 0x0448000);   // 32KB
    float* d2     = (float*)(ws + 0x1840000);   // 16KB
    float* x1p    = (float*)(ws + 0x1850000);   // 2MB
    int*   winner = (int*)  (ws + 0x1A50000);   // 256KB
    float* Wh2    = (float*)(ws + 0x1A90000);   // 128KB
    float* es2    = (float*)(ws + 0x1AB0000);   // 1KB
    float* ed2    = (float*)(ws + 0x1AB1000);   // 1KB
    float* hout2  = (float*)(ws + 0x1AB2000);   // 128KB
    float* part2  = (float*)(ws + 0x1AE2000);   // 64KB
    float* part1  = (float*)(ws + 0x1AF2000);   // 2KB

    k_setup <<<176, 256, 0, stream>>>(Wg, Weg, asrc, adst, aedge, Weo, aoe,
                                      feat, Wsn, asn, g1W, g1b,
                                      vs1, vd1, ve1, ve2, winner, h, gate1);
    k_mid   <<<32, 512, 0, stream>>>(h, gate1, vs1, vd1, eidx, part1, es1, ed1, winner);
    k_attn_z<<<512, 512, 0, stream>>>(adj, n2n, h, ve1, es1, ed1, z);
    k_houtp <<<128, 512, 0, stream>>>(z, Wg, Wp1, bp1, g2W, g2b, x1p, gate2);
    k_big2e <<<400, 1024, 0, stream>>>(x1p, Wo, aos, aod, gate2, eattr, Weg, ve2,
                                       Wh2, es2, ed2, part2, d2);
    k_fin   <<<265, 256, 0, stream>>>(winner, d2, es2, ed2, Wh2, part1, part2, hout2, out);
    k_tail  <<<1, 512, 0, stream>>>(hout2, Wp2, bp2, g3W, g3b, out);
}

// Round 12
// 137.702 us; speedup vs baseline: 1.1083x; 1.1083x over previous
//
#include <hip/hip_runtime.h>
#include <hip/hip_bf16.h>

__device__ __forceinline__ float sigm(float x) { return 1.f / (1.f + expf(-x)); }
__device__ __forceinline__ float lrelu(float x) { return x > 0.f ? x : 0.2f * x; }
__device__ __forceinline__ float eluf(float x) { return x > 0.f ? x : expf(x) - 1.f; }

#define NEGF (-9e15f)
#define MAXD 64   // max supported out-degree; P(deg>64) ~ 1e-40 for Binom(4096,1/512)

__device__ __forceinline__ float wave_sum(float v) {
    #pragma unroll
    for (int off = 32; off >= 1; off >>= 1) v += __shfl_xor(v, off);
    return v;
}
__device__ __forceinline__ float wave_max(float v) {
    #pragma unroll
    for (int off = 32; off >= 1; off >>= 1) v = fmaxf(v, __shfl_xor(v, off));
    return v;
}

// ---------------- K_setup: block-role fused independent preprocessing ----------------
// grid 176, block 256:
//   b 0..15   : vecs (vs1/vd1/ve1 for head b)
//   b 16..31  : ve2 (128 outputs/block)
//   b 32..47  : winner := -1 (clear; scatter happens next dispatch)
//   b 48..175 : SingleNodeAttention h + gate1 (4 nodes/block)
__global__ void k_setup(const float* __restrict__ Wg, const float* __restrict__ Weg,
                        const float* __restrict__ asrc, const float* __restrict__ adst,
                        const float* __restrict__ aedge, const float* __restrict__ Weo,
                        const float* __restrict__ aoe,
                        const float* __restrict__ feat, const float* __restrict__ Wsn,
                        const float* __restrict__ asn, const float* __restrict__ g1W,
                        const float* __restrict__ g1b,
                        float* __restrict__ vs1, float* __restrict__ vd1, float* __restrict__ ve1,
                        float* __restrict__ ve2, int* __restrict__ winner,
                        float* __restrict__ h, float* __restrict__ gate1) {
    int b = blockIdx.x, t = threadIdx.x, w = t >> 6, l = t & 63;
    __shared__ float fr[4][64];
    if (b < 16) {
        int hd = b;
        float s0 = asrc[hd * 128 + l],  s1 = asrc[hd * 128 + 64 + l];
        float d0 = adst[hd * 128 + l],  d1 = adst[hd * 128 + 64 + l];
        float e0 = aedge[hd * 128 + l], e1 = aedge[hd * 128 + 64 + l];
        for (int i = w; i < 64; i += 4) {
            const float* Wr = Wg  + ((size_t)hd * 64 + i) * 128;
            const float* Er = Weg + ((size_t)hd * 64 + i) * 128;
            float w1 = Wr[l], w2 = Wr[64 + l];
            float q1 = Er[l], q2 = Er[64 + l];
            float pS = wave_sum(w1 * s0 + w2 * s1);
            float pD = wave_sum(w1 * d0 + w2 * d1);
            float pE = wave_sum(q1 * e0 + q2 * e1);
            if (l == 0) { vs1[hd * 64 + i] = pS; vd1[hd * 64 + i] = pD; ve1[hd * 64 + i] = pE; }
        }
    } else if (b < 32) {
        int base = (b - 16) * 128;
        float a0 = aoe[l], a1 = aoe[64 + l];
        for (int k = 0; k < 32; k++) {
            int c = base + w * 32 + k;
            const float* Wr = Weo + (size_t)c * 128;
            float p = wave_sum(Wr[l] * a0 + Wr[64 + l] * a1);
            if (l == 0) ve2[c] = p;
        }
    } else if (b < 48) {
        int base = (b - 32) * 4096;
        #pragma unroll
        for (int k = 0; k < 16; k++) winner[base + k * 256 + t] = -1;
    } else {
        int n = (b - 48) * 4 + w;
        fr[w][l] = feat[n * 64 + l];
        __syncthreads();
        float acc = 0.f;
        #pragma unroll 8
        for (int i = 0; i < 64; i++) acc += fr[w][i] * Wsn[i * 64 + l];
        float p = wave_sum(acc * asn[l]);
        float coef = sigm(lrelu(p));
        float hv = eluf(coef * acc);
        h[n * 64 + l] = hv;
        float g = wave_sum(hv * g1W[l]);
        if (l == 0) gate1[n] = sigm(g + g1b[0]);
    }
}

// ---------------- K_mid: wsum1p (b 0..7) | es1/ed1 precompute (b 8..23) | scatter (b 24..31) ----------------
// grid 32, block 512
__global__ void k_mid(const float* __restrict__ h, const float* __restrict__ gate,
                      const float* __restrict__ vs1, const float* __restrict__ vd1,
                      const int* __restrict__ ei,
                      float* __restrict__ part1, float* __restrict__ es1, float* __restrict__ ed1,
                      int* __restrict__ winner) {
    int b = blockIdx.x, t = threadIdx.x;
    if (b < 8) {
        int nb = b, w = t >> 6, l = t & 63;
        __shared__ float mx[8], sm[8], al[512], pt[8][64];
        float g = gate[t];
        float m = wave_max(g);
        if (l == 0) mx[w] = m;
        __syncthreads();
        m = mx[0];
        #pragma unroll
        for (int i = 1; i < 8; i++) m = fmaxf(m, mx[i]);
        float p = expf(g - m);
        float Z = wave_sum(p);
        if (l == 0) sm[w] = Z;
        __syncthreads();
        Z = 0.f;
        #pragma unroll
        for (int i = 0; i < 8; i++) Z += sm[i];
        al[t] = p / Z;
        __syncthreads();
        int r0 = nb * 64 + w * 8;
        float acc = 0.f;
        #pragma unroll
        for (int r = 0; r < 8; r++) acc += al[r0 + r] * h[(r0 + r) * 64 + l];
        pt[w][l] = acc;
        __syncthreads();
        if (t < 64) {
            float o = 0.f;
            #pragma unroll
            for (int q = 0; q < 8; q++) o += pt[q][t];
            part1[nb * 64 + t] = o;
        }
    } else if (b < 24) {
        __shared__ float vsT[64][17], vdT[64][17];
        for (int idx = t; idx < 1024; idx += 512) {
            int i = idx & 63, hd = idx >> 6;
            vsT[i][hd] = vs1[hd * 64 + i];
            vdT[i][hd] = vd1[hd * 64 + i];
        }
        __syncthreads();
        int idx = (b - 8) * 512 + t;     // 0..8191
        int n = idx >> 4, hd = idx & 15;
        const float* hr = h + n * 64;
        float aS = 0.f, aD = 0.f;
        #pragma unroll 8
        for (int i = 0; i < 64; i++) {
            float hv = hr[i];
            aS += hv * vsT[i][hd];
            aD += hv * vdT[i][hd];
        }
        es1[hd * 512 + n] = aS;
        ed1[hd * 512 + n] = aD;
    } else {
        int e = (b - 24) * 512 + t;      // 0..4095
        int s = ei[e] >> 1, d = ei[4096 + e] >> 1;
        atomicMax(&winner[s * 256 + d], e);   // last edge index wins (np .set semantics)
    }
}

// ---------------- K_attn_z: sparse GAT1 attention -> z[s][hd][0:64] = sum_j a*h[d_j] ----------------
// grid 512 (s), block 512
__global__ void k_attn_z(const float* __restrict__ adj, const float* __restrict__ n2n,
                         const float* __restrict__ h, const float* __restrict__ ve1,
                         const float* __restrict__ es1, const float* __restrict__ ed1,
                         float* __restrict__ z) {
    int s = blockIdx.x, t = threadIdx.x, w = t >> 6, l = t & 63;
    __shared__ float vlT[64][17];
    __shared__ float hrow[MAXD][65], nrow[MAXD][65];
    __shared__ float eh[16][65], ah[16][65];
    __shared__ float esr[16];
    __shared__ int dlist[MAXD];
    __shared__ int wbase[8];
    __shared__ int nnz_s;

    for (int idx = t; idx < 1024; idx += 512) vlT[idx & 63][idx >> 6] = ve1[(idx >> 6) * 64 + (idx & 63)];
    if (t < 16) esr[t] = es1[t * 512 + s];
    float a = adj[s * 512 + t];
    unsigned long long mask = __ballot(a > 0.f);
    if (l == 0) wbase[w] = __popcll(mask);
    __syncthreads();
    if (t == 0) {
        int run = 0;
        #pragma unroll
        for (int i = 0; i < 8; i++) { int c = wbase[i]; wbase[i] = run; run += c; }
        nnz_s = run;
    }
    __syncthreads();
    if (a > 0.f) {
        int slot = wbase[w] + __popcll(mask & ((1ULL << l) - 1ULL));
        if (slot < MAXD) dlist[slot] = t;
    }
    __syncthreads();
    int nnz = min(nnz_s, MAXD);

    if (nnz == 0) {
        __shared__ float part[8][64];
        int i = t & 63, q = t >> 6;
        float acc = 0.f;
        for (int d = q * 64; d < q * 64 + 64; d++) acc += h[d * 64 + i];
        part[q][i] = acc;
        __syncthreads();
        if (t < 64) {
            float sum = 0.f;
            #pragma unroll
            for (int q2 = 0; q2 < 8; q2++) sum += part[q2][t];
            float v = sum * (1.f / 512.f);
            for (int hd = 0; hd < 16; hd++) z[(size_t)s * 1024 + hd * 64 + t] = v;
        }
        return;
    }

    for (int base = 0; base < nnz; base += 8) {
        int j = base + (t >> 6);
        if (j < nnz) {
            int d = dlist[j];
            hrow[j][l] = h[d * 64 + l];
            nrow[j][l] = n2n[((size_t)s * 512 + d) * 64 + l];
        }
    }
    __syncthreads();
    for (int jb = 0; jb < nnz; jb += 32) {
        int j = jb + (t >> 4), hd = t & 15;
        if (j < nnz) {
            float ee = 0.f;
            #pragma unroll 8
            for (int i = 0; i < 64; i++) ee += nrow[j][i] * vlT[i][hd];
            eh[hd][j] = lrelu(esr[hd] + ed1[hd * 512 + dlist[j]] + ee);
        }
    }
    __syncthreads();
    if (t < 16) {
        float m = -1e30f;
        for (int j = 0; j < nnz; j++) m = fmaxf(m, eh[t][j]);
        float Z = 0.f;
        for (int j = 0; j < nnz; j++) { float p = expf(eh[t][j] - m); ah[t][j] = p; Z += p; }
        float inv = 1.f / Z;
        for (int j = 0; j < nnz; j++) ah[t][j] *= inv;
    }
    __syncthreads();
    int hd = t >> 5, i0 = t & 31;
    float a0 = 0.f, a1 = 0.f;
    for (int j = 0; j < nnz; j++) {
        float aj = ah[hd][j];
        a0 += aj * hrow[j][i0];
        a1 += aj * hrow[j][i0 + 32];
    }
    z[(size_t)s * 1024 + hd * 64 + i0]      = a0;
    z[(size_t)s * 1024 + hd * 64 + i0 + 32] = a1;
}

// ---------------- K_houtg: hout[s][hd*128+c] = elu( z[s][hd]·Wg[hd][:,c] ) ----------------
// grid (64 s-tiles, 16 hd), block 128
__global__ void k_houtg(const float* __restrict__ z, const float* __restrict__ Wg,
                        float* __restrict__ hout) {
    int sb = blockIdx.x, hd = blockIdx.y, c = threadIdx.x;
    __shared__ float zt[8][64];
    int s0 = sb * 8;
    for (int idx = c; idx < 512; idx += 128) {
        int r = idx >> 6, i = idx & 63;
        zt[r][i] = z[(size_t)(s0 + r) * 1024 + hd * 64 + i];
    }
    __syncthreads();
    float acc[8] = {0, 0, 0, 0, 0, 0, 0, 0};
    const float* W = Wg + (size_t)hd * 8192 + c;
    #pragma unroll 8
    for (int i = 0; i < 64; i++) {
        float wv = W[(size_t)i * 128];
        #pragma unroll
        for (int r = 0; r < 8; r++) acc[r] += zt[r][i] * wv;
    }
    #pragma unroll
    for (int r = 0; r < 8; r++)
        hout[(size_t)(s0 + r) * 2048 + hd * 128 + c] = eluf(acc[r]);
}

// ---------------- K_pool1g2: edge_pool1 + gate2 fused ----------------
// grid 256, block 256
__global__ void k_pool1g2(const float* __restrict__ x, const float* __restrict__ Wp,
                          const float* __restrict__ bp, const float* __restrict__ g2W,
                          const float* __restrict__ g2b,
                          float* __restrict__ xo, float* __restrict__ gate2) {
    int k = blockIdx.x, t = threadIdx.x, w = t >> 6, l = t & 63;
    __shared__ float sd[4], sg[4];
    float p = 0.f;
    for (int f = t; f < 2048; f += 256)
        p += x[(size_t)(2 * k) * 2048 + f] * Wp[f] + x[(size_t)(2 * k + 1) * 2048 + f] * Wp[2048 + f];
    p = wave_sum(p);
    if (l == 0) sd[w] = p;
    __syncthreads();
    float sc = sigm(sd[0] + sd[1] + sd[2] + sd[3] + bp[0]);
    float pg = 0.f;
    for (int f = t; f < 2048; f += 256) {
        float v = x[(size_t)(2 * k) * 2048 + f] + x[(size_t)(2 * k + 1) * 2048 + f];
        xo[(size_t)k * 2048 + f] = v * sc;
        pg += v * g2W[f];
    }
    pg = wave_sum(pg);
    if (l == 0) sg[w] = pg;
    __syncthreads();
    if (t == 0) gate2[k] = sigm(sc * (sg[0] + sg[1] + sg[2] + sg[3]) + g2b[0]);
}

// ---------------- K_big2e: wh2 (b 0..127) | wsum2p (b 128..143) | edot (b 144..399) ----------------
// grid 400, block 1024
__global__ void k_big2e(const float* __restrict__ x, const float* __restrict__ Wo,
                        const float* __restrict__ aos, const float* __restrict__ aod,
                        const float* __restrict__ gate2, const float* __restrict__ eattr,
                        const float* __restrict__ Weg, const float* __restrict__ ve2,
                        float* __restrict__ Wh2, float* __restrict__ es2, float* __restrict__ ed2,
                        float* __restrict__ part2, float* __restrict__ d2) {
    int b = blockIdx.x, t = threadIdx.x;
    if (b < 128) {
        int n0 = b * 2;
        int ks = t >> 7, c = t & 127;
        __shared__ float xr[2][2048];
        __shared__ float part[8][2][128];
        __shared__ float rs[4], rd[4];
        for (int idx = t; idx < 4096; idx += 1024) xr[idx >> 11][idx & 2047] = x[(size_t)n0 * 2048 + idx];
        __syncthreads();
        float a0 = 0.f, a1 = 0.f;
        const float* W  = Wo + (size_t)(ks * 256) * 128 + c;
        const float* x0 = xr[0] + ks * 256;
        const float* x1 = xr[1] + ks * 256;
        #pragma unroll 8
        for (int i = 0; i < 256; i++) { float w = W[(size_t)i * 128]; a0 += x0[i] * w; a1 += x1[i] * w; }
        part[ks][0][c] = a0;
        part[ks][1][c] = a1;
        __syncthreads();
        if (t < 256) {
            int r = t >> 7, cc = t & 127;
            float a = 0.f;
            #pragma unroll
            for (int k = 0; k < 8; k++) a += part[k][r][cc];
            Wh2[(n0 + r) * 128 + cc] = a;
            float ps = wave_sum(a * aos[cc]);
            float pd = wave_sum(a * aod[cc]);
            if ((t & 63) == 0) { rs[t >> 6] = ps; rd[t >> 6] = pd; }
        }
        __syncthreads();
        if (t == 0) { es2[n0] = rs[0] + rs[1]; ed2[n0] = rd[0] + rd[1]; }
        if (t == 1) { es2[n0 + 1] = rs[2] + rs[3]; ed2[n0 + 1] = rd[2] + rd[3]; }
    } else if (b < 144) {
        int wb = b - 128;                 // 0..15
        int grp = t >> 8, tt = t & 255;   // 4 groups of 256
        int tile = wb * 4 + grp;          // 0..63
        int cb = tile >> 3, nb = tile & 7;
        __shared__ float mx[4][4], sm[4][4], al[4][256];
        int w4 = tt >> 6, l = tt & 63;
        float g = gate2[tt];
        float m = wave_max(g);
        if (l == 0) mx[grp][w4] = m;
        __syncthreads();
        m = fmaxf(fmaxf(mx[grp][0], mx[grp][1]), fmaxf(mx[grp][2], mx[grp][3]));
        float p = expf(g - m);
        float Z = wave_sum(p);
        if (l == 0) sm[grp][w4] = Z;
        __syncthreads();
        Z = sm[grp][0] + sm[grp][1] + sm[grp][2] + sm[grp][3];
        al[grp][tt] = p / Z;
        __syncthreads();
        int c = cb * 256 + tt;
        int n0 = nb * 32;
        float acc = 0.f;
        #pragma unroll 8
        for (int n = n0; n < n0 + 32; n++) acc += al[grp][n] * x[(size_t)n * 2048 + c];
        part2[nb * 2048 + c] = acc;
    } else {
        // edot: 16 edges/block; thread = (head hd = t>>6 in 0..15, l = t&63 -> float2 channels)
        int e0 = (b - 144) * 16;
        int hd = t >> 6, l = t & 63;
        __shared__ float ea[16][64];
        __shared__ float sd[16][16];
        ea[t >> 6][t & 63] = eattr[(size_t)(e0 + (t >> 6)) * 64 + (t & 63)];
        __syncthreads();
        float2 acc[16];
        #pragma unroll
        for (int r = 0; r < 16; r++) acc[r] = make_float2(0.f, 0.f);
        const float2* W2 = (const float2*)(Weg + (size_t)hd * 8192) + l;   // row stride = 64 float2
        #pragma unroll 4
        for (int i = 0; i < 64; i++) {
            float2 wv = W2[i * 64];
            #pragma unroll
            for (int r = 0; r < 16; r++) {
                float a = ea[r][i];
                acc[r].x += a * wv.x;
                acc[r].y += a * wv.y;
            }
        }
        float2 v2 = ((const float2*)ve2)[hd * 64 + l];
        #pragma unroll
        for (int r = 0; r < 16; r++) {
            float p = eluf(acc[r].x) * v2.x + eluf(acc[r].y) * v2.y;
            p = wave_sum(p);
            if (l == 0) sd[r][hd] = p;
        }
        __syncthreads();
        if (t < 16) {
            float s16 = 0.f;
            #pragma unroll
            for (int k = 0; k < 16; k++) s16 += sd[t][k];
            d2[e0 + t] = s16;
        }
    }
}

// ---------------- K_fin: attn2 (b 0..255) | wsumr (b 256..264) ----------------
// grid 265, block 256
__global__ void k_fin(const int* __restrict__ winner, const float* __restrict__ d2,
                      const float* __restrict__ es2, const float* __restrict__ ed2,
                      const float* __restrict__ Wh2, const float* __restrict__ part1,
                      const float* __restrict__ part2,
                      float* __restrict__ hout2, float* __restrict__ out) {
    int b = blockIdx.x, t = threadIdx.x;
    if (b < 256) {
        int s = b, w = t >> 6, l = t & 63;
        __shared__ float mx[4], sm[4], at[256], part[2][128];
        int win = winner[s * 256 + t];
        float e;
        if (win >= 0) e = lrelu(es2[s] + ed2[t] + d2[win]);
        else e = NEGF;
        float m = wave_max(e);
        if (l == 0) mx[w] = m;
        __syncthreads();
        m = fmaxf(fmaxf(mx[0], mx[1]), fmaxf(mx[2], mx[3]));
        float p = expf(e - m);
        float Z = wave_sum(p);
        if (l == 0) sm[w] = Z;
        __syncthreads();
        Z = sm[0] + sm[1] + sm[2] + sm[3];
        at[t] = p / Z;
        __syncthreads();
        int c = t & 127, hf = t >> 7;
        float acc = 0.f;
        for (int d = hf * 128; d < hf * 128 + 128; d++)
            acc += at[d] * Wh2[d * 128 + c];
        part[hf][c] = acc;
        __syncthreads();
        if (t < 128) hout2[s * 128 + t] = part[0][t] + part[1][t];   // concat=False: no elu
    } else if (b == 256) {
        if (t < 64) {
            float o = 0.f;
            #pragma unroll
            for (int nb = 0; nb < 8; nb++) o += part1[nb * 64 + t];
            out[t] = o;
        }
    } else {
        int c = (b - 257) * 256 + t;
        float o = 0.f;
        #pragma unroll
        for (int nb = 0; nb < 8; nb++) o += part2[nb * 2048 + c];
        out[64 + c] = o;
    }
}

// ---------------- K_tail: edge_pool2 + gate3 + global-attn3, single block ----------------
// grid 1, block 512
__global__ void k_tail(const float* __restrict__ hout2, const float* __restrict__ Wp,
                       const float* __restrict__ bp, const float* __restrict__ g3W,
                       const float* __restrict__ g3b, float* __restrict__ out) {
    int t = threadIdx.x, w = t >> 6, l = t & 63;
    __shared__ float x2s[128][129];
    __shared__ float gt[128];
    __shared__ float mx[2], sm[2], al[128], part[4][128];
    float bpv = bp[0], g3bv = g3b[0];
    for (int rr = 0; rr < 16; rr++) {
        int k = w * 16 + rr;
        float a0  = hout2[(size_t)(2 * k) * 128 + l];
        float a0b = hout2[(size_t)(2 * k) * 128 + 64 + l];
        float a1  = hout2[(size_t)(2 * k + 1) * 128 + l];
        float a1b = hout2[(size_t)(2 * k + 1) * 128 + 64 + l];
        float p = a0 * Wp[l] + a0b * Wp[64 + l] + a1 * Wp[128 + l] + a1b * Wp[192 + l];
        p = wave_sum(p);
        float sc = sigm(p + bpv);
        float v  = (a0 + a1) * sc;
        float vb = (a0b + a1b) * sc;
        x2s[k][l] = v;
        x2s[k][64 + l] = vb;
        float g = wave_sum(v * g3W[l] + vb * g3W[64 + l]);
        if (l == 0) gt[k] = sigm(g + g3bv);
    }
    __syncthreads();
    if (t < 128) {
        float g = gt[t];
        float m = wave_max(g);
        if (l == 0) mx[w] = m;
    }
    __syncthreads();
    if (t < 128) {
        float g = gt[t];
        float m = fmaxf(mx[0], mx[1]);
        float p = expf(g - m);
        float Z = wave_sum(p);
        if (l == 0) sm[w] = Z;
        al[t] = p;
    }
    __syncthreads();
    float invZ = 1.f / (sm[0] + sm[1]);
    int q = t >> 7, c = t & 127;
    float acc = 0.f;
    for (int n = q * 32; n < q * 32 + 32; n++) acc += al[n] * x2s[n][c];
    part[q][c] = acc * invZ;
    __syncthreads();
    if (t < 128) out[2112 + t] = part[0][t] + part[1][t] + part[2][t] + part[3][t];
}

extern "C" void kernel_launch(void* const* d_in, const int* in_sizes, int n_in,
                              void* d_out, int out_size, void* d_ws, size_t ws_size,
                              hipStream_t stream) {
    const float* feat  = (const float*)d_in[0];
    const int*   eidx  = (const int*)d_in[1];
    const float* eattr = (const float*)d_in[2];
    const float* adj   = (const float*)d_in[3];
    const float* n2n   = (const float*)d_in[4];
    const float* Wsn   = (const float*)d_in[5];
    const float* asn   = (const float*)d_in[6];
    const float* Wg    = (const float*)d_in[7];
    const float* Weg   = (const float*)d_in[8];
    const float* asrc  = (const float*)d_in[9];
    const float* adst  = (const float*)d_in[10];
    const float* aedge = (const float*)d_in[11];
    const float* Wp1   = (const float*)d_in[12];
    const float* bp1   = (const float*)d_in[13];
    const float* Wo    = (const float*)d_in[14];
    const float* Weo   = (const float*)d_in[15];
    const float* aos   = (const float*)d_in[16];
    const float* aod   = (const float*)d_in[17];
    const float* aoe   = (const float*)d_in[18];
    const float* Wp2   = (const float*)d_in[19];
    const float* bp2   = (const float*)d_in[20];
    const float* g1W   = (const float*)d_in[21];
    const float* g1b   = (const float*)d_in[22];
    const float* g2W   = (const float*)d_in[23];
    const float* g2b   = (const float*)d_in[24];
    const float* g3W   = (const float*)d_in[25];
    const float* g3b   = (const float*)d_in[26];
    float* out = (float*)d_out;

    char* ws = (char*)d_ws;
    float* h      = (float*)(ws + 0x0000000);   // 128KB
    float* z      = (float*)(ws + 0x0020000);   // 2MB
    float* ve1    = (float*)(ws + 0x0430000);   // 4KB
    float* ve2    = (float*)(ws + 0x0431000);   // 8KB
    float* gate1  = (float*)(ws + 0x0433000);   // 2KB
    float* gate2  = (float*)(ws + 0x0434000);   // 1KB
    float* vs1    = (float*)(ws + 0x0436000);   // 4KB
    float* vd1    = (float*)(ws + 0x0438000);   // 4KB
    float* es1    = (float*)(ws + 0x0440000);   // 32KB
    float* ed1    = (float*)(ws + 0x0448000);   // 32KB
    float* hout1  = (float*)(ws + 0x1440000);   // 4MB
    float* d2     = (float*)(ws + 0x1840000);   // 16KB
    float* x1p    = (float*)(ws + 0x1850000);   // 2MB
    int*   winner = (int*)  (ws + 0x1A50000);   // 256KB
    float* Wh2    = (float*)(ws + 0x1A90000);   // 128KB
    float* es2    = (float*)(ws + 0x1AB0000);   // 1KB
    float* ed2    = (float*)(ws + 0x1AB1000);   // 1KB
    float* hout2  = (float*)(ws + 0x1AB2000);   // 128KB
    float* part2  = (float*)(ws + 0x1AE2000);   // 64KB
    float* part1  = (float*)(ws + 0x1AF2000);   // 2KB

    k_setup  <<<176, 256, 0, stream>>>(Wg, Weg, asrc, adst, aedge, Weo, aoe,
                                       feat, Wsn, asn, g1W, g1b,
                                       vs1, vd1, ve1, ve2, winner, h, gate1);
    k_mid    <<<32, 512, 0, stream>>>(h, gate1, vs1, vd1, eidx, part1, es1, ed1, winner);
    k_attn_z <<<512, 512, 0, stream>>>(adj, n2n, h, ve1, es1, ed1, z);
    k_houtg  <<<dim3(64, 16), 128, 0, stream>>>(z, Wg, hout1);
    k_pool1g2<<<256, 256, 0, stream>>>(hout1, Wp1, bp1, g2W, g2b, x1p, gate2);
    k_big2e  <<<400, 1024, 0, stream>>>(x1p, Wo, aos, aod, gate2, eattr, Weg, ve2,
                                        Wh2, es2, ed2, part2, d2);
    k_fin    <<<265, 256, 0, stream>>>(winner, d2, es2, ed2, Wh2, part1, part2, hout2, out);
    k_tail   <<<1, 512, 0, stream>>>(hout2, Wp2, bp2, g3W, g3b, out);
}

// Round 13
// 131.269 us; speedup vs baseline: 1.1627x; 1.0490x over previous
//
#include <hip/hip_runtime.h>
#include <hip/hip_bf16.h>

__device__ __forceinline__ float sigm(float x) { return 1.f / (1.f + expf(-x)); }
__device__ __forceinline__ float lrelu(float x) { return x > 0.f ? x : 0.2f * x; }
__device__ __forceinline__ float eluf(float x) { return x > 0.f ? x : expf(x) - 1.f; }

#define NEGF (-9e15f)
#define MAXD 64   // max supported out-degree; P(deg>64) ~ 1e-40 for Binom(4096,1/512)

__device__ __forceinline__ float wave_sum(float v) {
    #pragma unroll
    for (int off = 32; off >= 1; off >>= 1) v += __shfl_xor(v, off);
    return v;
}
__device__ __forceinline__ float wave_max(float v) {
    #pragma unroll
    for (int off = 32; off >= 1; off >>= 1) v = fmaxf(v, __shfl_xor(v, off));
    return v;
}

// ---------------- K_setup: block-role fused independent preprocessing ----------------
// grid 176, block 256:
//   b 0..15   : vecs (vs1/vd1/ve1 for head b)
//   b 16..31  : ve2 (128 outputs/block)
//   b 32..47  : winner := -1 (clear; scatter happens next dispatch)
//   b 48..175 : SingleNodeAttention h + gate1 (4 nodes/block)
__global__ void k_setup(const float* __restrict__ Wg, const float* __restrict__ Weg,
                        const float* __restrict__ asrc, const float* __restrict__ adst,
                        const float* __restrict__ aedge, const float* __restrict__ Weo,
                        const float* __restrict__ aoe,
                        const float* __restrict__ feat, const float* __restrict__ Wsn,
                        const float* __restrict__ asn, const float* __restrict__ g1W,
                        const float* __restrict__ g1b,
                        float* __restrict__ vs1, float* __restrict__ vd1, float* __restrict__ ve1,
                        float* __restrict__ ve2, int* __restrict__ winner,
                        float* __restrict__ h, float* __restrict__ gate1) {
    int b = blockIdx.x, t = threadIdx.x, w = t >> 6, l = t & 63;
    __shared__ float fr[4][64];
    if (b < 16) {
        int hd = b;
        float s0 = asrc[hd * 128 + l],  s1 = asrc[hd * 128 + 64 + l];
        float d0 = adst[hd * 128 + l],  d1 = adst[hd * 128 + 64 + l];
        float e0 = aedge[hd * 128 + l], e1 = aedge[hd * 128 + 64 + l];
        for (int i = w; i < 64; i += 4) {
            const float* Wr = Wg  + ((size_t)hd * 64 + i) * 128;
            const float* Er = Weg + ((size_t)hd * 64 + i) * 128;
            float w1 = Wr[l], w2 = Wr[64 + l];
            float q1 = Er[l], q2 = Er[64 + l];
            float pS = wave_sum(w1 * s0 + w2 * s1);
            float pD = wave_sum(w1 * d0 + w2 * d1);
            float pE = wave_sum(q1 * e0 + q2 * e1);
            if (l == 0) { vs1[hd * 64 + i] = pS; vd1[hd * 64 + i] = pD; ve1[hd * 64 + i] = pE; }
        }
    } else if (b < 32) {
        int base = (b - 16) * 128;
        float a0 = aoe[l], a1 = aoe[64 + l];
        for (int k = 0; k < 32; k++) {
            int c = base + w * 32 + k;
            const float* Wr = Weo + (size_t)c * 128;
            float p = wave_sum(Wr[l] * a0 + Wr[64 + l] * a1);
            if (l == 0) ve2[c] = p;
        }
    } else if (b < 48) {
        int base = (b - 32) * 4096;
        #pragma unroll
        for (int k = 0; k < 16; k++) winner[base + k * 256 + t] = -1;
    } else {
        int n = (b - 48) * 4 + w;
        fr[w][l] = feat[n * 64 + l];
        __syncthreads();
        float acc = 0.f;
        #pragma unroll 8
        for (int i = 0; i < 64; i++) acc += fr[w][i] * Wsn[i * 64 + l];
        float p = wave_sum(acc * asn[l]);
        float coef = sigm(lrelu(p));
        float hv = eluf(coef * acc);
        h[n * 64 + l] = hv;
        float g = wave_sum(hv * g1W[l]);
        if (l == 0) gate1[n] = sigm(g + g1b[0]);
    }
}

// ---------------- K_mid: wsum1p (b 0..7) | es1/ed1 precompute (b 8..23) | scatter (b 24..31) ----------------
// grid 32, block 512
__global__ void k_mid(const float* __restrict__ h, const float* __restrict__ gate,
                      const float* __restrict__ vs1, const float* __restrict__ vd1,
                      const int* __restrict__ ei,
                      float* __restrict__ part1, float* __restrict__ es1, float* __restrict__ ed1,
                      int* __restrict__ winner) {
    int b = blockIdx.x, t = threadIdx.x;
    if (b < 8) {
        int nb = b, w = t >> 6, l = t & 63;
        __shared__ float mx[8], sm[8], al[512], pt[8][64];
        float g = gate[t];
        float m = wave_max(g);
        if (l == 0) mx[w] = m;
        __syncthreads();
        m = mx[0];
        #pragma unroll
        for (int i = 1; i < 8; i++) m = fmaxf(m, mx[i]);
        float p = expf(g - m);
        float Z = wave_sum(p);
        if (l == 0) sm[w] = Z;
        __syncthreads();
        Z = 0.f;
        #pragma unroll
        for (int i = 0; i < 8; i++) Z += sm[i];
        al[t] = p / Z;
        __syncthreads();
        int r0 = nb * 64 + w * 8;
        float acc = 0.f;
        #pragma unroll
        for (int r = 0; r < 8; r++) acc += al[r0 + r] * h[(r0 + r) * 64 + l];
        pt[w][l] = acc;
        __syncthreads();
        if (t < 64) {
            float o = 0.f;
            #pragma unroll
            for (int q = 0; q < 8; q++) o += pt[q][t];
            part1[nb * 64 + t] = o;
        }
    } else if (b < 24) {
        __shared__ float vsT[64][17], vdT[64][17];
        for (int idx = t; idx < 1024; idx += 512) {
            int i = idx & 63, hd = idx >> 6;
            vsT[i][hd] = vs1[hd * 64 + i];
            vdT[i][hd] = vd1[hd * 64 + i];
        }
        __syncthreads();
        int idx = (b - 8) * 512 + t;     // 0..8191
        int n = idx >> 4, hd = idx & 15;
        const float* hr = h + n * 64;
        float aS = 0.f, aD = 0.f;
        #pragma unroll 8
        for (int i = 0; i < 64; i++) {
            float hv = hr[i];
            aS += hv * vsT[i][hd];
            aD += hv * vdT[i][hd];
        }
        es1[hd * 512 + n] = aS;
        ed1[hd * 512 + n] = aD;
    } else {
        int e = (b - 24) * 512 + t;      // 0..4095
        int s = ei[e] >> 1, d = ei[4096 + e] >> 1;
        atomicMax(&winner[s * 256 + d], e);   // last edge index wins (np .set semantics)
    }
}

// ---------------- K_attn_ze: attn_z (b 0..511) | edot (b 512..1023, R9-proven) ----------------
// grid 1024, block 512
__global__ void k_attn_ze(const float* __restrict__ adj, const float* __restrict__ n2n,
                          const float* __restrict__ h, const float* __restrict__ ve1,
                          const float* __restrict__ es1, const float* __restrict__ ed1,
                          const float* __restrict__ eattr, const float* __restrict__ Weg,
                          const float* __restrict__ ve2,
                          float* __restrict__ z, float* __restrict__ d2) {
    int b = blockIdx.x, t = threadIdx.x, w = t >> 6, l = t & 63;
    if (b >= 512) {
        // edot: 8 edges/block; thread = (hd = t>>5, q = t&31 -> 4 channels); float4 acc[8] = 32 regs
        int e0 = (b - 512) * 8;
        int hd = t >> 5, q = t & 31;
        __shared__ float ea[8][64];
        __shared__ float sd2[8][8];
        ea[t >> 6][t & 63] = eattr[(size_t)(e0 + (t >> 6)) * 64 + (t & 63)];
        __syncthreads();
        float4 acc[8];
        #pragma unroll
        for (int r = 0; r < 8; r++) acc[r] = make_float4(0.f, 0.f, 0.f, 0.f);
        const float4* W4 = (const float4*)Weg + (size_t)hd * 2048 + q;
        #pragma unroll 4
        for (int i = 0; i < 64; i++) {
            float4 wv = W4[i * 32];
            #pragma unroll
            for (int r = 0; r < 8; r++) {
                float a = ea[r][i];
                acc[r].x += a * wv.x; acc[r].y += a * wv.y;
                acc[r].z += a * wv.z; acc[r].w += a * wv.w;
            }
        }
        float4 v2 = ((const float4*)ve2)[hd * 32 + q];
        #pragma unroll
        for (int r = 0; r < 8; r++) {
            float p = eluf(acc[r].x) * v2.x + eluf(acc[r].y) * v2.y
                    + eluf(acc[r].z) * v2.z + eluf(acc[r].w) * v2.w;
            p = wave_sum(p);              // sums 2 heads per wave; heads also sum into d2
            if (l == 0) sd2[r][w] = p;
        }
        __syncthreads();
        if (t < 8) {
            float s8 = 0.f;
            #pragma unroll
            for (int k = 0; k < 8; k++) s8 += sd2[t][k];
            d2[e0 + t] = s8;
        }
        return;
    }
    int s = b;
    __shared__ float vlT[64][17];
    __shared__ float hrow[MAXD][65], nrow[MAXD][65];
    __shared__ float eh[16][65], ah[16][65];
    __shared__ float esr[16];
    __shared__ int dlist[MAXD];
    __shared__ int wbase[8];
    __shared__ int nnz_s;

    for (int idx = t; idx < 1024; idx += 512) vlT[idx & 63][idx >> 6] = ve1[(idx >> 6) * 64 + (idx & 63)];
    if (t < 16) esr[t] = es1[t * 512 + s];
    float a = adj[s * 512 + t];
    unsigned long long mask = __ballot(a > 0.f);
    if (l == 0) wbase[w] = __popcll(mask);
    __syncthreads();
    if (t == 0) {
        int run = 0;
        #pragma unroll
        for (int i = 0; i < 8; i++) { int c = wbase[i]; wbase[i] = run; run += c; }
        nnz_s = run;
    }
    __syncthreads();
    if (a > 0.f) {
        int slot = wbase[w] + __popcll(mask & ((1ULL << l) - 1ULL));
        if (slot < MAXD) dlist[slot] = t;
    }
    __syncthreads();
    int nnz = min(nnz_s, MAXD);

    if (nnz == 0) {
        __shared__ float part[8][64];
        int i = t & 63, q = t >> 6;
        float acc = 0.f;
        for (int d = q * 64; d < q * 64 + 64; d++) acc += h[d * 64 + i];
        part[q][i] = acc;
        __syncthreads();
        if (t < 64) {
            float sum = 0.f;
            #pragma unroll
            for (int q2 = 0; q2 < 8; q2++) sum += part[q2][t];
            float v = sum * (1.f / 512.f);
            for (int hd = 0; hd < 16; hd++) z[(size_t)s * 1024 + hd * 64 + t] = v;
        }
        return;
    }

    for (int base = 0; base < nnz; base += 8) {
        int j = base + (t >> 6);
        if (j < nnz) {
            int d = dlist[j];
            hrow[j][l] = h[d * 64 + l];
            nrow[j][l] = n2n[((size_t)s * 512 + d) * 64 + l];
        }
    }
    __syncthreads();
    for (int jb = 0; jb < nnz; jb += 32) {
        int j = jb + (t >> 4), hd = t & 15;
        if (j < nnz) {
            float ee = 0.f;
            #pragma unroll 8
            for (int i = 0; i < 64; i++) ee += nrow[j][i] * vlT[i][hd];
            eh[hd][j] = lrelu(esr[hd] + ed1[hd * 512 + dlist[j]] + ee);
        }
    }
    __syncthreads();
    if (t < 16) {
        float m = -1e30f;
        for (int j = 0; j < nnz; j++) m = fmaxf(m, eh[t][j]);
        float Z = 0.f;
        for (int j = 0; j < nnz; j++) { float p = expf(eh[t][j] - m); ah[t][j] = p; Z += p; }
        float inv = 1.f / Z;
        for (int j = 0; j < nnz; j++) ah[t][j] *= inv;
    }
    __syncthreads();
    int hd = t >> 5, i0 = t & 31;
    float a0 = 0.f, a1 = 0.f;
    for (int j = 0; j < nnz; j++) {
        float aj = ah[hd][j];
        a0 += aj * hrow[j][i0];
        a1 += aj * hrow[j][i0 + 32];
    }
    z[(size_t)s * 1024 + hd * 64 + i0]      = a0;
    z[(size_t)s * 1024 + hd * 64 + i0 + 32] = a1;
}

// ---------------- K_houtg: hout[s][hd*128+c] = elu( z[s][hd]·Wg[hd][:,c] ) ----------------
// grid (64 s-tiles, 16 hd), block 128
__global__ void k_houtg(const float* __restrict__ z, const float* __restrict__ Wg,
                        float* __restrict__ hout) {
    int sb = blockIdx.x, hd = blockIdx.y, c = threadIdx.x;
    __shared__ float zt[8][64];
    int s0 = sb * 8;
    for (int idx = c; idx < 512; idx += 128) {
        int r = idx >> 6, i = idx & 63;
        zt[r][i] = z[(size_t)(s0 + r) * 1024 + hd * 64 + i];
    }
    __syncthreads();
    float acc[8] = {0, 0, 0, 0, 0, 0, 0, 0};
    const float* W = Wg + (size_t)hd * 8192 + c;
    #pragma unroll 8
    for (int i = 0; i < 64; i++) {
        float wv = W[(size_t)i * 128];
        #pragma unroll
        for (int r = 0; r < 8; r++) acc[r] += zt[r][i] * wv;
    }
    #pragma unroll
    for (int r = 0; r < 8; r++)
        hout[(size_t)(s0 + r) * 2048 + hd * 128 + c] = eluf(acc[r]);
}

// ---------------- K_pool1g2: edge_pool1 + gate2 fused ----------------
// grid 256, block 256
__global__ void k_pool1g2(const float* __restrict__ x, const float* __restrict__ Wp,
                          const float* __restrict__ bp, const float* __restrict__ g2W,
                          const float* __restrict__ g2b,
                          float* __restrict__ xo, float* __restrict__ gate2) {
    int k = blockIdx.x, t = threadIdx.x, w = t >> 6, l = t & 63;
    __shared__ float sd[4], sg[4];
    float p = 0.f;
    for (int f = t; f < 2048; f += 256)
        p += x[(size_t)(2 * k) * 2048 + f] * Wp[f] + x[(size_t)(2 * k + 1) * 2048 + f] * Wp[2048 + f];
    p = wave_sum(p);
    if (l == 0) sd[w] = p;
    __syncthreads();
    float sc = sigm(sd[0] + sd[1] + sd[2] + sd[3] + bp[0]);
    float pg = 0.f;
    for (int f = t; f < 2048; f += 256) {
        float v = x[(size_t)(2 * k) * 2048 + f] + x[(size_t)(2 * k + 1) * 2048 + f];
        xo[(size_t)k * 2048 + f] = v * sc;
        pg += v * g2W[f];
    }
    pg = wave_sum(pg);
    if (l == 0) sg[w] = pg;
    __syncthreads();
    if (t == 0) gate2[k] = sigm(sc * (sg[0] + sg[1] + sg[2] + sg[3]) + g2b[0]);
}

// ---------------- K_big2: wh2 (b 0..127) | wsum2p (b 128..143) ----------------
// grid 144, block 1024
__global__ void k_big2(const float* __restrict__ x, const float* __restrict__ Wo,
                       const float* __restrict__ aos, const float* __restrict__ aod,
                       const float* __restrict__ gate2,
                       float* __restrict__ Wh2, float* __restrict__ es2, float* __restrict__ ed2,
                       float* __restrict__ part2) {
    int b = blockIdx.x, t = threadIdx.x;
    if (b < 128) {
        int n0 = b * 2;
        int ks = t >> 7, c = t & 127;
        __shared__ float xr[2][2048];
        __shared__ float part[8][2][128];
        __shared__ float rs[4], rd[4];
        for (int idx = t; idx < 4096; idx += 1024) xr[idx >> 11][idx & 2047] = x[(size_t)n0 * 2048 + idx];
        __syncthreads();
        float a0 = 0.f, a1 = 0.f;
        const float* W  = Wo + (size_t)(ks * 256) * 128 + c;
        const float* x0 = xr[0] + ks * 256;
        const float* x1 = xr[1] + ks * 256;
        #pragma unroll 8
        for (int i = 0; i < 256; i++) { float w = W[(size_t)i * 128]; a0 += x0[i] * w; a1 += x1[i] * w; }
        part[ks][0][c] = a0;
        part[ks][1][c] = a1;
        __syncthreads();
        if (t < 256) {
            int r = t >> 7, cc = t & 127;
            float a = 0.f;
            #pragma unroll
            for (int k = 0; k < 8; k++) a += part[k][r][cc];
            Wh2[(n0 + r) * 128 + cc] = a;
            float ps = wave_sum(a * aos[cc]);
            float pd = wave_sum(a * aod[cc]);
            if ((t & 63) == 0) { rs[t >> 6] = ps; rd[t >> 6] = pd; }
        }
        __syncthreads();
        if (t == 0) { es2[n0] = rs[0] + rs[1]; ed2[n0] = rd[0] + rd[1]; }
        if (t == 1) { es2[n0 + 1] = rs[2] + rs[3]; ed2[n0 + 1] = rd[2] + rd[3]; }
    } else {
        int wb = b - 128;                 // 0..15
        int grp = t >> 8, tt = t & 255;   // 4 groups of 256
        int tile = wb * 4 + grp;          // 0..63
        int cb = tile >> 3, nb = tile & 7;
        __shared__ float mx[4][4], sm[4][4], al[4][256];
        int w4 = tt >> 6, l = tt & 63;
        float g = gate2[tt];
        float m = wave_max(g);
        if (l == 0) mx[grp][w4] = m;
        __syncthreads();
        m = fmaxf(fmaxf(mx[grp][0], mx[grp][1]), fmaxf(mx[grp][2], mx[grp][3]));
        float p = expf(g - m);
        float Z = wave_sum(p);
        if (l == 0) sm[grp][w4] = Z;
        __syncthreads();
        Z = sm[grp][0] + sm[grp][1] + sm[grp][2] + sm[grp][3];
        al[grp][tt] = p / Z;
        __syncthreads();
        int c = cb * 256 + tt;
        int n0 = nb * 32;
        float acc = 0.f;
        #pragma unroll 8
        for (int n = n0; n < n0 + 32; n++) acc += al[grp][n] * x[(size_t)n * 2048 + c];
        part2[nb * 2048 + c] = acc;
    }
}

// ---------------- K_fin: attn2 (b 0..255) | wsumr (b 256..264) ----------------
// grid 265, block 256
__global__ void k_fin(const int* __restrict__ winner, const float* __restrict__ d2,
                      const float* __restrict__ es2, const float* __restrict__ ed2,
                      const float* __restrict__ Wh2, const float* __restrict__ part1,
                      const float* __restrict__ part2,
                      float* __restrict__ hout2, float* __restrict__ out) {
    int b = blockIdx.x, t = threadIdx.x;
    if (b < 256) {
        int s = b, w = t >> 6, l = t & 63;
        __shared__ float mx[4], sm[4], at[256], part[2][128];
        int win = winner[s * 256 + t];
        float e;
        if (win >= 0) e = lrelu(es2[s] + ed2[t] + d2[win]);
        else e = NEGF;
        float m = wave_max(e);
        if (l == 0) mx[w] = m;
        __syncthreads();
        m = fmaxf(fmaxf(mx[0], mx[1]), fmaxf(mx[2], mx[3]));
        float p = expf(e - m);
        float Z = wave_sum(p);
        if (l == 0) sm[w] = Z;
        __syncthreads();
        Z = sm[0] + sm[1] + sm[2] + sm[3];
        at[t] = p / Z;
        __syncthreads();
        int c = t & 127, hf = t >> 7;
        float acc = 0.f;
        for (int d = hf * 128; d < hf * 128 + 128; d++)
            acc += at[d] * Wh2[d * 128 + c];
        part[hf][c] = acc;
        __syncthreads();
        if (t < 128) hout2[s * 128 + t] = part[0][t] + part[1][t];   // concat=False: no elu
    } else if (b == 256) {
        if (t < 64) {
            float o = 0.f;
            #pragma unroll
            for (int nb = 0; nb < 8; nb++) o += part1[nb * 64 + t];
            out[t] = o;
        }
    } else {
        int c = (b - 257) * 256 + t;
        float o = 0.f;
        #pragma unroll
        for (int nb = 0; nb < 8; nb++) o += part2[nb * 2048 + c];
        out[64 + c] = o;
    }
}

// ---------------- K_tail: edge_pool2 + gate3 + global-attn3, single block ----------------
// grid 1, block 512
__global__ void k_tail(const float* __restrict__ hout2, const float* __restrict__ Wp,
                       const float* __restrict__ bp, const float* __restrict__ g3W,
                       const float* __restrict__ g3b, float* __restrict__ out) {
    int t = threadIdx.x, w = t >> 6, l = t & 63;
    __shared__ float x2s[128][129];
    __shared__ float gt[128];
    __shared__ float mx[2], sm[2], al[128], part[4][128];
    float bpv = bp[0], g3bv = g3b[0];
    for (int rr = 0; rr < 16; rr++) {
        int k = w * 16 + rr;
        float a0  = hout2[(size_t)(2 * k) * 128 + l];
        float a0b = hout2[(size_t)(2 * k) * 128 + 64 + l];
        float a1  = hout2[(size_t)(2 * k + 1) * 128 + l];
        float a1b = hout2[(size_t)(2 * k + 1) * 128 + 64 + l];
        float p = a0 * Wp[l] + a0b * Wp[64 + l] + a1 * Wp[128 + l] + a1b * Wp[192 + l];
        p = wave_sum(p);
        float sc = sigm(p + bpv);
        float v  = (a0 + a1) * sc;
        float vb = (a0b + a1b) * sc;
        x2s[k][l] = v;
        x2s[k][64 + l] = vb;
        float g = wave_sum(v * g3W[l] + vb * g3W[64 + l]);
        if (l == 0) gt[k] = sigm(g + g3bv);
    }
    __syncthreads();
    if (t < 128) {
        float g = gt[t];
        float m = wave_max(g);
        if (l == 0) mx[w] = m;
    }
    __syncthreads();
    if (t < 128) {
        float g = gt[t];
        float m = fmaxf(mx[0], mx[1]);
        float p = expf(g - m);
        float Z = wave_sum(p);
        if (l == 0) sm[w] = Z;
        al[t] = p;
    }
    __syncthreads();
    float invZ = 1.f / (sm[0] + sm[1]);
    int q = t >> 7, c = t & 127;
    float acc = 0.f;
    for (int n = q * 32; n < q * 32 + 32; n++) acc += al[n] * x2s[n][c];
    part[q][c] = acc * invZ;
    __syncthreads();
    if (t < 128) out[2112 + t] = part[0][t] + part[1][t] + part[2][t] + part[3][t];
}

extern "C" void kernel_launch(void* const* d_in, const int* in_sizes, int n_in,
                              void* d_out, int out_size, void* d_ws, size_t ws_size,
                              hipStream_t stream) {
    const float* feat  = (const float*)d_in[0];
    const int*   eidx  = (const int*)d_in[1];
    const float* eattr = (const float*)d_in[2];
    const float* adj   = (const float*)d_in[3];
    const float* n2n   = (const float*)d_in[4];
    const float* Wsn   = (const float*)d_in[5];
    const float* asn   = (const float*)d_in[6];
    const float* Wg    = (const float*)d_in[7];
    const float* Weg   = (const float*)d_in[8];
    const float* asrc  = (const float*)d_in[9];
    const float* adst  = (const float*)d_in[10];
    const float* aedge = (const float*)d_in[11];
    const float* Wp1   = (const float*)d_in[12];
    const float* bp1   = (const float*)d_in[13];
    const float* Wo    = (const float*)d_in[14];
    const float* Weo   = (const float*)d_in[15];
    const float* aos   = (const float*)d_in[16];
    const float* aod   = (const float*)d_in[17];
    const float* aoe   = (const float*)d_in[18];
    const float* Wp2   = (const float*)d_in[19];
    const float* bp2   = (const float*)d_in[20];
    const float* g1W   = (const float*)d_in[21];
    const float* g1b   = (const float*)d_in[22];
    const float* g2W   = (const float*)d_in[23];
    const float* g2b   = (const float*)d_in[24];
    const float* g3W   = (const float*)d_in[25];
    const float* g3b   = (const float*)d_in[26];
    float* out = (float*)d_out;

    char* ws = (char*)d_ws;
    float* h      = (float*)(ws + 0x0000000);   // 128KB
    float* z      = (float*)(ws + 0x0020000);   // 2MB
    float* ve1    = (float*)(ws + 0x0430000);   // 4KB
    float* ve2    = (float*)(ws + 0x0431000);   // 8KB
    float* gate1  = (float*)(ws + 0x0433000);   // 2KB
    float* gate2  = (float*)(ws + 0x0434000);   // 1KB
    float* vs1    = (float*)(ws + 0x0436000);   // 4KB
    float* vd1    = (float*)(ws + 0x0438000);   // 4KB
    float* es1    = (float*)(ws + 0x0440000);   // 32KB
    float* ed1    = (float*)(ws + 0x0448000);   // 32KB
    float* hout1  = (float*)(ws + 0x1440000);   // 4MB
    float* d2     = (float*)(ws + 0x1840000);   // 16KB
    float* x1p    = (float*)(ws + 0x1850000);   // 2MB
    int*   winner = (int*)  (ws + 0x1A50000);   // 256KB
    float* Wh2    = (float*)(ws + 0x1A90000);   // 128KB
    float* es2    = (float*)(ws + 0x1AB0000);   // 1KB
    float* ed2    = (float*)(ws + 0x1AB1000);   // 1KB
    float* hout2  = (float*)(ws + 0x1AB2000);   // 128KB
    float* part2  = (float*)(ws + 0x1AE2000);   // 64KB
    float* part1  = (float*)(ws + 0x1AF2000);   // 2KB

    k_setup  <<<176, 256, 0, stream>>>(Wg, Weg, asrc, adst, aedge, Weo, aoe,
                                       feat, Wsn, asn, g1W, g1b,
                                       vs1, vd1, ve1, ve2, winner, h, gate1);
    k_mid    <<<32, 512, 0, stream>>>(h, gate1, vs1, vd1, eidx, part1, es1, ed1, winner);
    k_attn_ze<<<1024, 512, 0, stream>>>(adj, n2n, h, ve1, es1, ed1, eattr, Weg, ve2, z, d2);
    k_houtg  <<<dim3(64, 16), 128, 0, stream>>>(z, Wg, hout1);
    k_pool1g2<<<256, 256, 0, stream>>>(hout1, Wp1, bp1, g2W, g2b, x1p, gate2);
    k_big2   <<<144, 1024, 0, stream>>>(x1p, Wo, aos, aod, gate2, Wh2, es2, ed2, part2);
    k_fin    <<<265, 256, 0, stream>>>(winner, d2, es2, ed2, Wh2, part1, part2, hout2, out);
    k_tail   <<<1, 512, 0, stream>>>(hout2, Wp2, bp2, g3W, g3b, out);
}

// Round 14
// 130.923 us; speedup vs baseline: 1.1657x; 1.0026x over previous
//
#include <hip/hip_runtime.h>
#include <hip/hip_bf16.h>

__device__ __forceinline__ float sigm(float x) { return 1.f / (1.f + expf(-x)); }
__device__ __forceinline__ float lrelu(float x) { return x > 0.f ? x : 0.2f * x; }
__device__ __forceinline__ float eluf(float x) { return x > 0.f ? x : expf(x) - 1.f; }

#define NEGF (-9e15f)
#define MAXD 40   // max supported out-degree; deg ~ Binom(4096,1/512): mean 8, sigma 2.8 -> P(deg>40) ~ 1e-28

__device__ __forceinline__ float wave_sum(float v) {
    #pragma unroll
    for (int off = 32; off >= 1; off >>= 1) v += __shfl_xor(v, off);
    return v;
}
__device__ __forceinline__ float wave_max(float v) {
    #pragma unroll
    for (int off = 32; off >= 1; off >>= 1) v = fmaxf(v, __shfl_xor(v, off));
    return v;
}
// reduce within each 32-lane half of a wave64 (offs <=16 never cross the half boundary)
__device__ __forceinline__ float half_sum(float v) {
    #pragma unroll
    for (int off = 16; off >= 1; off >>= 1) v += __shfl_xor(v, off);
    return v;
}
__device__ __forceinline__ float half_max(float v) {
    #pragma unroll
    for (int off = 16; off >= 1; off >>= 1) v = fmaxf(v, __shfl_xor(v, off));
    return v;
}

// ---------------- K_setup: block-role fused independent preprocessing ----------------
// grid 176, block 256:
//   b 0..15   : vecs (vs1/vd1/ve1 for head b)
//   b 16..31  : ve2 (128 outputs/block)
//   b 32..47  : winner := -1 (clear; scatter happens next dispatch)
//   b 48..175 : SingleNodeAttention h + gate1 (4 nodes/block)
__global__ void k_setup(const float* __restrict__ Wg, const float* __restrict__ Weg,
                        const float* __restrict__ asrc, const float* __restrict__ adst,
                        const float* __restrict__ aedge, const float* __restrict__ Weo,
                        const float* __restrict__ aoe,
                        const float* __restrict__ feat, const float* __restrict__ Wsn,
                        const float* __restrict__ asn, const float* __restrict__ g1W,
                        const float* __restrict__ g1b,
                        float* __restrict__ vs1, float* __restrict__ vd1, float* __restrict__ ve1,
                        float* __restrict__ ve2, int* __restrict__ winner,
                        float* __restrict__ h, float* __restrict__ gate1) {
    int b = blockIdx.x, t = threadIdx.x, w = t >> 6, l = t & 63;
    __shared__ float fr[4][64];
    if (b < 16) {
        int hd = b;
        float s0 = asrc[hd * 128 + l],  s1 = asrc[hd * 128 + 64 + l];
        float d0 = adst[hd * 128 + l],  d1 = adst[hd * 128 + 64 + l];
        float e0 = aedge[hd * 128 + l], e1 = aedge[hd * 128 + 64 + l];
        for (int i = w; i < 64; i += 4) {
            const float* Wr = Wg  + ((size_t)hd * 64 + i) * 128;
            const float* Er = Weg + ((size_t)hd * 64 + i) * 128;
            float w1 = Wr[l], w2 = Wr[64 + l];
            float q1 = Er[l], q2 = Er[64 + l];
            float pS = wave_sum(w1 * s0 + w2 * s1);
            float pD = wave_sum(w1 * d0 + w2 * d1);
            float pE = wave_sum(q1 * e0 + q2 * e1);
            if (l == 0) { vs1[hd * 64 + i] = pS; vd1[hd * 64 + i] = pD; ve1[hd * 64 + i] = pE; }
        }
    } else if (b < 32) {
        int base = (b - 16) * 128;
        float a0 = aoe[l], a1 = aoe[64 + l];
        for (int k = 0; k < 32; k++) {
            int c = base + w * 32 + k;
            const float* Wr = Weo + (size_t)c * 128;
            float p = wave_sum(Wr[l] * a0 + Wr[64 + l] * a1);
            if (l == 0) ve2[c] = p;
        }
    } else if (b < 48) {
        int base = (b - 32) * 4096;
        #pragma unroll
        for (int k = 0; k < 16; k++) winner[base + k * 256 + t] = -1;
    } else {
        int n = (b - 48) * 4 + w;
        fr[w][l] = feat[n * 64 + l];
        __syncthreads();
        float acc = 0.f;
        #pragma unroll 8
        for (int i = 0; i < 64; i++) acc += fr[w][i] * Wsn[i * 64 + l];
        float p = wave_sum(acc * asn[l]);
        float coef = sigm(lrelu(p));
        float hv = eluf(coef * acc);
        h[n * 64 + l] = hv;
        float g = wave_sum(hv * g1W[l]);
        if (l == 0) gate1[n] = sigm(g + g1b[0]);
    }
}

// ---------------- K_mid: wsum1p (b 0..7) | es1/ed1 precompute (b 8..23) | scatter (b 24..31) ----------------
// grid 32, block 512
__global__ void k_mid(const float* __restrict__ h, const float* __restrict__ gate,
                      const float* __restrict__ vs1, const float* __restrict__ vd1,
                      const int* __restrict__ ei,
                      float* __restrict__ part1, float* __restrict__ es1, float* __restrict__ ed1,
                      int* __restrict__ winner) {
    int b = blockIdx.x, t = threadIdx.x;
    if (b < 8) {
        int nb = b, w = t >> 6, l = t & 63;
        __shared__ float mx[8], sm[8], al[512], pt[8][64];
        float g = gate[t];
        float m = wave_max(g);
        if (l == 0) mx[w] = m;
        __syncthreads();
        m = mx[0];
        #pragma unroll
        for (int i = 1; i < 8; i++) m = fmaxf(m, mx[i]);
        float p = expf(g - m);
        float Z = wave_sum(p);
        if (l == 0) sm[w] = Z;
        __syncthreads();
        Z = 0.f;
        #pragma unroll
        for (int i = 0; i < 8; i++) Z += sm[i];
        al[t] = p / Z;
        __syncthreads();
        int r0 = nb * 64 + w * 8;
        float acc = 0.f;
        #pragma unroll
        for (int r = 0; r < 8; r++) acc += al[r0 + r] * h[(r0 + r) * 64 + l];
        pt[w][l] = acc;
        __syncthreads();
        if (t < 64) {
            float o = 0.f;
            #pragma unroll
            for (int q = 0; q < 8; q++) o += pt[q][t];
            part1[nb * 64 + t] = o;
        }
    } else if (b < 24) {
        __shared__ float vsT[64][17], vdT[64][17];
        for (int idx = t; idx < 1024; idx += 512) {
            int i = idx & 63, hd = idx >> 6;
            vsT[i][hd] = vs1[hd * 64 + i];
            vdT[i][hd] = vd1[hd * 64 + i];
        }
        __syncthreads();
        int idx = (b - 8) * 512 + t;     // 0..8191
        int n = idx >> 4, hd = idx & 15;
        const float* hr = h + n * 64;
        float aS = 0.f, aD = 0.f;
        #pragma unroll 8
        for (int i = 0; i < 64; i++) {
            float hv = hr[i];
            aS += hv * vsT[i][hd];
            aD += hv * vdT[i][hd];
        }
        es1[hd * 512 + n] = aS;
        ed1[hd * 512 + n] = aD;
    } else {
        int e = (b - 24) * 512 + t;      // 0..4095
        int s = ei[e] >> 1, d = ei[4096 + e] >> 1;
        atomicMax(&winner[s * 256 + d], e);   // last edge index wins (np .set semantics)
    }
}

// ---------------- K_attn_ze: attn_z (b 0..511) | edot (b 512..1023) ----------------
// grid 1024, block 512. attn branch LDS ~32KB -> ~5 blocks/CU.
__global__ void k_attn_ze(const float* __restrict__ adj, const float* __restrict__ n2n,
                          const float* __restrict__ h, const float* __restrict__ ve1,
                          const float* __restrict__ es1, const float* __restrict__ ed1,
                          const float* __restrict__ eattr, const float* __restrict__ Weg,
                          const float* __restrict__ ve2,
                          float* __restrict__ z, float* __restrict__ d2) {
    int b = blockIdx.x, t = threadIdx.x, w = t >> 6, l = t & 63;
    if (b >= 512) {
        // edot: 8 edges/block; thread = (hd = t>>5, q = t&31 -> 4 channels); float4 acc[8] = 32 regs
        int e0 = (b - 512) * 8;
        int hd = t >> 5, q = t & 31;
        __shared__ float ea[8][64];
        __shared__ float sd2[8][8];
        ea[t >> 6][t & 63] = eattr[(size_t)(e0 + (t >> 6)) * 64 + (t & 63)];
        __syncthreads();
        float4 acc[8];
        #pragma unroll
        for (int r = 0; r < 8; r++) acc[r] = make_float4(0.f, 0.f, 0.f, 0.f);
        const float4* W4 = (const float4*)Weg + (size_t)hd * 2048 + q;
        #pragma unroll 4
        for (int i = 0; i < 64; i++) {
            float4 wv = W4[i * 32];
            #pragma unroll
            for (int r = 0; r < 8; r++) {
                float a = ea[r][i];
                acc[r].x += a * wv.x; acc[r].y += a * wv.y;
                acc[r].z += a * wv.z; acc[r].w += a * wv.w;
            }
        }
        float4 v2 = ((const float4*)ve2)[hd * 32 + q];
        #pragma unroll
        for (int r = 0; r < 8; r++) {
            float p = eluf(acc[r].x) * v2.x + eluf(acc[r].y) * v2.y
                    + eluf(acc[r].z) * v2.z + eluf(acc[r].w) * v2.w;
            p = wave_sum(p);
            if (l == 0) sd2[r][w] = p;
        }
        __syncthreads();
        if (t < 8) {
            float s8 = 0.f;
            #pragma unroll
            for (int k = 0; k < 8; k++) s8 += sd2[t][k];
            d2[e0 + t] = s8;
        }
        return;
    }
    int s = b;
    __shared__ float vlT[64][17];
    __shared__ float hrow[MAXD][65], nrow[MAXD][65];
    __shared__ float eh[16][48], ah[16][48];
    __shared__ float esr[16];
    __shared__ int dlist[MAXD];
    __shared__ int wbase[8];
    __shared__ int nnz_s;
    __shared__ float part[8][64];

    for (int idx = t; idx < 1024; idx += 512) vlT[idx & 63][idx >> 6] = ve1[(idx >> 6) * 64 + (idx & 63)];
    if (t < 16) esr[t] = es1[t * 512 + s];
    float a = adj[s * 512 + t];
    unsigned long long mask = __ballot(a > 0.f);
    if (l == 0) wbase[w] = __popcll(mask);
    __syncthreads();
    if (t == 0) {
        int run = 0;
        #pragma unroll
        for (int i = 0; i < 8; i++) { int c = wbase[i]; wbase[i] = run; run += c; }
        nnz_s = run;
    }
    __syncthreads();
    if (a > 0.f) {
        int slot = wbase[w] + __popcll(mask & ((1ULL << l) - 1ULL));
        if (slot < MAXD) dlist[slot] = t;
    }
    __syncthreads();
    int nnz = min(nnz_s, MAXD);

    if (nnz == 0) {
        int i = t & 63, q = t >> 6;
        float acc = 0.f;
        for (int d = q * 64; d < q * 64 + 64; d++) acc += h[d * 64 + i];
        part[q][i] = acc;
        __syncthreads();
        if (t < 64) {
            float sum = 0.f;
            #pragma unroll
            for (int q2 = 0; q2 < 8; q2++) sum += part[q2][t];
            float v = sum * (1.f / 512.f);
            for (int hd = 0; hd < 16; hd++) z[(size_t)s * 1024 + hd * 64 + t] = v;
        }
        return;
    }

    for (int base = 0; base < nnz; base += 8) {
        int j = base + (t >> 6);
        if (j < nnz) {
            int d = dlist[j];
            hrow[j][l] = h[d * 64 + l];
            nrow[j][l] = n2n[((size_t)s * 512 + d) * 64 + l];
        }
    }
    __syncthreads();
    for (int jb = 0; jb < nnz; jb += 32) {
        int j = jb + (t >> 4), hd = t & 15;
        if (j < nnz) {
            float ee = 0.f;
            #pragma unroll 8
            for (int i = 0; i < 64; i++) ee += nrow[j][i] * vlT[i][hd];
            eh[hd][j] = lrelu(esr[hd] + ed1[hd * 512 + dlist[j]] + ee);
        }
    }
    __syncthreads();
    // wave-parallel per-head softmax: head = t>>5 (16 heads x 32-lane groups)
    {
        int hd = t >> 5, lane32 = t & 31;
        float v0 = (lane32 < nnz) ? eh[hd][lane32] : -1e30f;
        float v1 = (lane32 + 32 < nnz) ? eh[hd][lane32 + 32] : -1e30f;
        float m = half_max(fmaxf(v0, v1));
        float p0 = (lane32 < nnz) ? expf(v0 - m) : 0.f;
        float p1 = (lane32 + 32 < nnz) ? expf(v1 - m) : 0.f;
        float Z = half_sum(p0 + p1);
        float inv = 1.f / Z;
        if (lane32 < nnz) ah[hd][lane32] = p0 * inv;
        if (lane32 + 32 < nnz) ah[hd][lane32 + 32] = p1 * inv;
    }
    __syncthreads();
    int hd = t >> 5, i0 = t & 31;
    float a0 = 0.f, a1 = 0.f;
    for (int j = 0; j < nnz; j++) {
        float aj = ah[hd][j];
        a0 += aj * hrow[j][i0];
        a1 += aj * hrow[j][i0 + 32];
    }
    z[(size_t)s * 1024 + hd * 64 + i0]      = a0;
    z[(size_t)s * 1024 + hd * 64 + i0 + 32] = a1;
}

// ---------------- K_houtg: hout[s][hd*128+c] = elu( z[s][hd]·Wg[hd][:,c] ) ----------------
// grid (64 s-tiles, 16 hd), block 128
__global__ void k_houtg(const float* __restrict__ z, const float* __restrict__ Wg,
                        float* __restrict__ hout) {
    int sb = blockIdx.x, hd = blockIdx.y, c = threadIdx.x;
    __shared__ float zt[8][64];
    int s0 = sb * 8;
    for (int idx = c; idx < 512; idx += 128) {
        int r = idx >> 6, i = idx & 63;
        zt[r][i] = z[(size_t)(s0 + r) * 1024 + hd * 64 + i];
    }
    __syncthreads();
    float acc[8] = {0, 0, 0, 0, 0, 0, 0, 0};
    const float* W = Wg + (size_t)hd * 8192 + c;
    #pragma unroll 8
    for (int i = 0; i < 64; i++) {
        float wv = W[(size_t)i * 128];
        #pragma unroll
        for (int r = 0; r < 8; r++) acc[r] += zt[r][i] * wv;
    }
    #pragma unroll
    for (int r = 0; r < 8; r++)
        hout[(size_t)(s0 + r) * 2048 + hd * 128 + c] = eluf(acc[r]);
}

// ---------------- K_pool1g2: edge_pool1 + gate2 fused ----------------
// grid 256, block 256
__global__ void k_pool1g2(const float* __restrict__ x, const float* __restrict__ Wp,
                          const float* __restrict__ bp, const float* __restrict__ g2W,
                          const float* __restrict__ g2b,
                          float* __restrict__ xo, float* __restrict__ gate2) {
    int k = blockIdx.x, t = threadIdx.x, w = t >> 6, l = t & 63;
    __shared__ float sd[4], sg[4];
    float p = 0.f;
    for (int f = t; f < 2048; f += 256)
        p += x[(size_t)(2 * k) * 2048 + f] * Wp[f] + x[(size_t)(2 * k + 1) * 2048 + f] * Wp[2048 + f];
    p = wave_sum(p);
    if (l == 0) sd[w] = p;
    __syncthreads();
    float sc = sigm(sd[0] + sd[1] + sd[2] + sd[3] + bp[0]);
    float pg = 0.f;
    for (int f = t; f < 2048; f += 256) {
        float v = x[(size_t)(2 * k) * 2048 + f] + x[(size_t)(2 * k + 1) * 2048 + f];
        xo[(size_t)k * 2048 + f] = v * sc;
        pg += v * g2W[f];
    }
    pg = wave_sum(pg);
    if (l == 0) sg[w] = pg;
    __syncthreads();
    if (t == 0) gate2[k] = sigm(sc * (sg[0] + sg[1] + sg[2] + sg[3]) + g2b[0]);
}

// ---------------- K_big2: wh2 (b 0..127) | wsum2p (b 128..143) ----------------
// grid 144, block 1024
__global__ void k_big2(const float* __restrict__ x, const float* __restrict__ Wo,
                       const float* __restrict__ aos, const float* __restrict__ aod,
                       const float* __restrict__ gate2,
                       float* __restrict__ Wh2, float* __restrict__ es2, float* __restrict__ ed2,
                       float* __restrict__ part2) {
    int b = blockIdx.x, t = threadIdx.x;
    if (b < 128) {
        int n0 = b * 2;
        int ks = t >> 7, c = t & 127;
        __shared__ float xr[2][2048];
        __shared__ float part[8][2][128];
        __shared__ float rs[4], rd[4];
        for (int idx = t; idx < 4096; idx += 1024) xr[idx >> 11][idx & 2047] = x[(size_t)n0 * 2048 + idx];
        __syncthreads();
        float a0 = 0.f, a1 = 0.f;
        const float* W  = Wo + (size_t)(ks * 256) * 128 + c;
        const float* x0 = xr[0] + ks * 256;
        const float* x1 = xr[1] + ks * 256;
        #pragma unroll 8
        for (int i = 0; i < 256; i++) { float w = W[(size_t)i * 128]; a0 += x0[i] * w; a1 += x1[i] * w; }
        part[ks][0][c] = a0;
        part[ks][1][c] = a1;
        __syncthreads();
        if (t < 256) {
            int r = t >> 7, cc = t & 127;
            float a = 0.f;
            #pragma unroll
            for (int k = 0; k < 8; k++) a += part[k][r][cc];
            Wh2[(n0 + r) * 128 + cc] = a;
            float ps = wave_sum(a * aos[cc]);
            float pd = wave_sum(a * aod[cc]);
            if ((t & 63) == 0) { rs[t >> 6] = ps; rd[t >> 6] = pd; }
        }
        __syncthreads();
        if (t == 0) { es2[n0] = rs[0] + rs[1]; ed2[n0] = rd[0] + rd[1]; }
        if (t == 1) { es2[n0 + 1] = rs[2] + rs[3]; ed2[n0 + 1] = rd[2] + rd[3]; }
    } else {
        int wb = b - 128;                 // 0..15
        int grp = t >> 8, tt = t & 255;   // 4 groups of 256
        int tile = wb * 4 + grp;          // 0..63
        int cb = tile >> 3, nb = tile & 7;
        __shared__ float mx[4][4], sm[4][4], al[4][256];
        int w4 = tt >> 6, l = tt & 63;
        float g = gate2[tt];
        float m = wave_max(g);
        if (l == 0) mx[grp][w4] = m;
        __syncthreads();
        m = fmaxf(fmaxf(mx[grp][0], mx[grp][1]), fmaxf(mx[grp][2], mx[grp][3]));
        float p = expf(g - m);
        float Z = wave_sum(p);
        if (l == 0) sm[grp][w4] = Z;
        __syncthreads();
        Z = sm[grp][0] + sm[grp][1] + sm[grp][2] + sm[grp][3];
        al[grp][tt] = p / Z;
        __syncthreads();
        int c = cb * 256 + tt;
        int n0 = nb * 32;
        float acc = 0.f;
        #pragma unroll 8
        for (int n = n0; n < n0 + 32; n++) acc += al[grp][n] * x[(size_t)n * 2048 + c];
        part2[nb * 2048 + c] = acc;
    }
}

// ---------------- K_fin: attn2 (b 0..255) | wsumr (b 256..264) ----------------
// grid 265, block 256
__global__ void k_fin(const int* __restrict__ winner, const float* __restrict__ d2,
                      const float* __restrict__ es2, const float* __restrict__ ed2,
                      const float* __restrict__ Wh2, const float* __restrict__ part1,
                      const float* __restrict__ part2,
                      float* __restrict__ hout2, float* __restrict__ out) {
    int b = blockIdx.x, t = threadIdx.x;
    if (b < 256) {
        int s = b, w = t >> 6, l = t & 63;
        __shared__ float mx[4], sm[4], at[256], part[2][128];
        int win = winner[s * 256 + t];
        float e;
        if (win >= 0) e = lrelu(es2[s] + ed2[t] + d2[win]);
        else e = NEGF;
        float m = wave_max(e);
        if (l == 0) mx[w] = m;
        __syncthreads();
        m = fmaxf(fmaxf(mx[0], mx[1]), fmaxf(mx[2], mx[3]));
        float p = expf(e - m);
        float Z = wave_sum(p);
        if (l == 0) sm[w] = Z;
        __syncthreads();
        Z = sm[0] + sm[1] + sm[2] + sm[3];
        at[t] = p / Z;
        __syncthreads();
        int c = t & 127, hf = t >> 7;
        float acc = 0.f;
        for (int d = hf * 128; d < hf * 128 + 128; d++)
            acc += at[d] * Wh2[d * 128 + c];
        part[hf][c] = acc;
        __syncthreads();
        if (t < 128) hout2[s * 128 + t] = part[0][t] + part[1][t];   // concat=False: no elu
    } else if (b == 256) {
        if (t < 64) {
            float o = 0.f;
            #pragma unroll
            for (int nb = 0; nb < 8; nb++) o += part1[nb * 64 + t];
            out[t] = o;
        }
    } else {
        int c = (b - 257) * 256 + t;
        float o = 0.f;
        #pragma unroll
        for (int nb = 0; nb < 8; nb++) o += part2[nb * 2048 + c];
        out[64 + c] = o;
    }
}

// ---------------- K_tail: edge_pool2 + gate3 + global-attn3, single block ----------------
// grid 1, block 512
__global__ void k_tail(const float* __restrict__ hout2, const float* __restrict__ Wp,
                       const float* __restrict__ bp, const float* __restrict__ g3W,
                       const float* __restrict__ g3b, float* __restrict__ out) {
    int t = threadIdx.x, w = t >> 6, l = t & 63;
    __shared__ float x2s[128][129];
    __shared__ float gt[128];
    __shared__ float mx[2], sm[2], al[128], part[4][128];
    float bpv = bp[0], g3bv = g3b[0];
    for (int rr = 0; rr < 16; rr++) {
        int k = w * 16 + rr;
        float a0  = hout2[(size_t)(2 * k) * 128 + l];
        float a0b = hout2[(size_t)(2 * k) * 128 + 64 + l];
        float a1  = hout2[(size_t)(2 * k + 1) * 128 + l];
        float a1b = hout2[(size_t)(2 * k + 1) * 128 + 64 + l];
        float p = a0 * Wp[l] + a0b * Wp[64 + l] + a1 * Wp[128 + l] + a1b * Wp[192 + l];
        p = wave_sum(p);
        float sc = sigm(p + bpv);
        float v  = (a0 + a1) * sc;
        float vb = (a0b + a1b) * sc;
        x2s[k][l] = v;
        x2s[k][64 + l] = vb;
        float g = wave_sum(v * g3W[l] + vb * g3W[64 + l]);
        if (l == 0) gt[k] = sigm(g + g3bv);
    }
    __syncthreads();
    if (t < 128) {
        float g = gt[t];
        float m = wave_max(g);
        if (l == 0) mx[w] = m;
    }
    __syncthreads();
    if (t < 128) {
        float g = gt[t];
        float m = fmaxf(mx[0], mx[1]);
        float p = expf(g - m);
        float Z = wave_sum(p);
        if (l == 0) sm[w] = Z;
        al[t] = p;
    }
    __syncthreads();
    float invZ = 1.f / (sm[0] + sm[1]);
    int q = t >> 7, c = t & 127;
    float acc = 0.f;
    for (int n = q * 32; n < q * 32 + 32; n++) acc += al[n] * x2s[n][c];
    part[q][c] = acc * invZ;
    __syncthreads();
    if (t < 128) out[2112 + t] = part[0][t] + part[1][t] + part[2][t] + part[3][t];
}

extern "C" void kernel_launch(void* const* d_in, const int* in_sizes, int n_in,
                              void* d_out, int out_size, void* d_ws, size_t ws_size,
                              hipStream_t stream) {
    const float* feat  = (const float*)d_in[0];
    const int*   eidx  = (const int*)d_in[1];
    const float* eattr = (const float*)d_in[2];
    const float* adj   = (const float*)d_in[3];
    const float* n2n   = (const float*)d_in[4];
    const float* Wsn   = (const float*)d_in[5];
    const float* asn   = (const float*)d_in[6];
    const float* Wg    = (const float*)d_in[7];
    const float* Weg   = (const float*)d_in[8];
    const float* asrc  = (const float*)d_in[9];
    const float* adst  = (const float*)d_in[10];
    const float* aedge = (const float*)d_in[11];
    const float* Wp1   = (const float*)d_in[12];
    const float* bp1   = (const float*)d_in[13];
    const float* Wo    = (const float*)d_in[14];
    const float* Weo   = (const float*)d_in[15];
    const float* aos   = (const float*)d_in[16];
    const float* aod   = (const float*)d_in[17];
    const float* aoe   = (const float*)d_in[18];
    const float* Wp2   = (const float*)d_in[19];
    const float* bp2   = (const float*)d_in[20];
    const float* g1W   = (const float*)d_in[21];
    const float* g1b   = (const float*)d_in[22];
    const float* g2W   = (const float*)d_in[23];
    const float* g2b   = (const float*)d_in[24];
    const float* g3W   = (const float*)d_in[25];
    const float* g3b   = (const float*)d_in[26];
    float* out = (float*)d_out;

    char* ws = (char*)d_ws;
    float* h      = (float*)(ws + 0x0000000);   // 128KB
    float* z      = (float*)(ws + 0x0020000);   // 2MB
    float* ve1    = (float*)(ws + 0x0430000);   // 4KB
    float* ve2    = (float*)(ws + 0x0431000);   // 8KB
    float* gate1  = (float*)(ws + 0x0433000);   // 2KB
    float* gate2  = (float*)(ws + 0x0434000);   // 1KB
    float* vs1    = (float*)(ws + 0x0436000);   // 4KB
    float* vd1    = (float*)(ws + 0x0438000);   // 4KB
    float* es1    = (float*)(ws + 0x0440000);   // 32KB
    float* ed1    = (float*)(ws + 0x0448000);   // 32KB
    float* hout1  = (float*)(ws + 0x1440000);   // 4MB
    float* d2     = (float*)(ws + 0x1840000);   // 16KB
    float* x1p    = (float*)(ws + 0x1850000);   // 2MB
    int*   winner = (int*)  (ws + 0x1A50000);   // 256KB
    float* Wh2    = (float*)(ws + 0x1A90000);   // 128KB
    float* es2    = (float*)(ws + 0x1AB0000);   // 1KB
    float* ed2    = (float*)(ws + 0x1AB1000);   // 1KB
    float* hout2  = (float*)(ws + 0x1AB2000);   // 128KB
    float* part2  = (float*)(ws + 0x1AE2000);   // 64KB
    float* part1  = (float*)(ws + 0x1AF2000);   // 2KB

    k_setup  <<<176, 256, 0, stream>>>(Wg, Weg, asrc, adst, aedge, Weo, aoe,
                                       feat, Wsn, asn, g1W, g1b,
                                       vs1, vd1, ve1, ve2, winner, h, gate1);
    k_mid    <<<32, 512, 0, stream>>>(h, gate1, vs1, vd1, eidx, part1, es1, ed1, winner);
    k_attn_ze<<<1024, 512, 0, stream>>>(adj, n2n, h, ve1, es1, ed1, eattr, Weg, ve2, z, d2);
    k_houtg  <<<dim3(64, 16), 128, 0, stream>>>(z, Wg, hout1);
    k_pool1g2<<<256, 256, 0, stream>>>(hout1, Wp1, bp1, g2W, g2b, x1p, gate2);
    k_big2   <<<144, 1024, 0, stream>>>(x1p, Wo, aos, aod, gate2, Wh2, es2, ed2, part2);
    k_fin    <<<265, 256, 0, stream>>>(winner, d2, es2, ed2, Wh2, part1, part2, hout2, out);
    k_tail   <<<1, 512, 0, stream>>>(hout2, Wp2, bp2, g3W, g3b, out);
}